// Round 2
// baseline (593.829 us; speedup 1.0000x reference)
//
#include <hip/hip_runtime.h>
#include <stdint.h>

typedef unsigned short u16;
typedef __attribute__((ext_vector_type(8))) short short8;
typedef __attribute__((ext_vector_type(4))) float f32x4;

__device__ __forceinline__ float b2f(u16 u){ union{unsigned i; float f;}v; v.i=((unsigned)u)<<16; return v.f; }
__device__ __forceinline__ u16 f2b(float f){ unsigned x=__float_as_uint(f); return (u16)((x + 0x7fffu + ((x>>16)&1u))>>16); }

#if __has_builtin(__builtin_amdgcn_exp2f)
#define EXP2F(x) __builtin_amdgcn_exp2f(x)
#else
#define EXP2F(x) exp2f(x)
#endif

__device__ __forceinline__ void async16(const void* g, void* l){
  __builtin_amdgcn_global_load_lds((const __attribute__((address_space(1))) void*)g,
                                   (__attribute__((address_space(3))) void*)l, 16, 0, 0);
}

// ---------------- LayerNorm (E=1024, one block per row) ----------------
// IN_F32=1: x is fp32; IN_F32=0: x is bf16(u16). gamma/beta fp32. Output bf16.
template<int IN_F32>
__global__ __launch_bounds__(256) void ln_kernel(const void* __restrict__ xin,
    const float* __restrict__ g, const float* __restrict__ b, u16* __restrict__ y)
{
  const int E = 1024;
  int row = blockIdx.x, t = threadIdx.x;
  float f0,f1,f2,f3;
  if (IN_F32){
    const float* xr = (const float*)xin + (size_t)row*E;
    float4 xv = *(const float4*)(xr + t*4);
    f0=xv.x; f1=xv.y; f2=xv.z; f3=xv.w;
  } else {
    const u16* xr = (const u16*)xin + (size_t)row*E;
    ushort4 xv = *(const ushort4*)(xr + t*4);
    f0=b2f(xv.x); f1=b2f(xv.y); f2=b2f(xv.z); f3=b2f(xv.w);
  }
  float s1 = f0+f1+f2+f3;
  float s2 = f0*f0+f1*f1+f2*f2+f3*f3;
  #pragma unroll
  for (int off=32; off>=1; off>>=1){ s1 += __shfl_xor(s1,off); s2 += __shfl_xor(s2,off); }
  __shared__ float red[8];
  int w = t>>6;
  if ((t&63)==0){ red[w]=s1; red[4+w]=s2; }
  __syncthreads();
  float S1 = red[0]+red[1]+red[2]+red[3];
  float S2 = red[4]+red[5]+red[6]+red[7];
  float mean = S1*(1.0f/E);
  float var  = S2*(1.0f/E) - mean*mean;
  float inv  = rsqrtf(var + 1e-5f);
  float4 gv = *(const float4*)(g + t*4);
  float4 bv = *(const float4*)(b + t*4);
  ushort4 o;
  o.x = f2b((f0-mean)*inv*gv.x+bv.x);
  o.y = f2b((f1-mean)*inv*gv.y+bv.y);
  o.z = f2b((f2-mean)*inv*gv.z+bv.z);
  o.w = f2b((f3-mean)*inv*gv.w+bv.w);
  *(ushort4*)(y + (size_t)row*E + t*4) = o;
}

// ---------------- fp32->bf16 64x64-tiled transpose ----------------
// dst[(c0+cc)*ld_dst + r0+rr] = src[(r0+rr)*ld_src + c0+cc]; grid=(C/64, R/64)
__global__ __launch_bounds__(256) void transpose_bt(const float* __restrict__ src, u16* __restrict__ dst,
                                                    int ld_src, int ld_dst)
{
  __shared__ u16 tile[64*66];
  int c0 = blockIdx.x*64, r0 = blockIdx.y*64;
  int t = threadIdx.x;
  #pragma unroll
  for (int i=0;i<16;++i){
    int lin = i*256 + t;
    int rr = lin>>6, cc = lin&63;
    tile[cc*66+rr] = f2b(src[(size_t)(r0+rr)*ld_src + c0+cc]);
  }
  __syncthreads();
  #pragma unroll
  for (int i=0;i<16;++i){
    int lin = i*256 + t;
    int cc = lin>>6, rr = lin&63;
    dst[(size_t)(c0+cc)*ld_dst + r0+rr] = tile[cc*66+rr];
  }
}

// ---------------- QKV weight repack: wq/wk/wv (H,E,hd) fp32 -> bf16 WqkvT[3072][1024] ----------------
__global__ __launch_bounds__(256) void qkv_repack(const float* __restrict__ wq, const float* __restrict__ wk,
                                                  const float* __restrict__ wv, u16* __restrict__ dst)
{
  __shared__ u16 tile[64*66];
  int e0 = blockIdx.x*64;
  int sel = blockIdx.y>>4, h = blockIdx.y&15;
  const float* src = (sel==0?wq:(sel==1?wk:wv)) + (size_t)h*1024*64;
  int t = threadIdx.x;
  #pragma unroll
  for (int i=0;i<16;++i){
    int lin=i*256+t; int rr=lin>>6, cc=lin&63;   // rr: e-offset, cc: k
    tile[cc*66+rr] = f2b(src[(size_t)(e0+rr)*64 + cc]);
  }
  __syncthreads();
  #pragma unroll
  for (int i=0;i<16;++i){
    int lin=i*256+t; int cc=lin>>6, rr=lin&63;
    dst[(size_t)(sel*1024 + h*64 + cc)*1024 + e0+rr] = tile[cc*66+rr];
  }
}

// ---------------- m97-style bf16 GEMM: C[M][N] = A[M][K] * Bt[N][K]^T ----------------
// 128x128 tile, 4 waves (2x2), mfma 16x16x32, global_load_lds width-16 staging.
// bias fp32; residual bf16; Cf!=null -> fp32 output, else bf16 to C.
__global__ __launch_bounds__(256) void gemm_bt(const u16* __restrict__ A, const u16* __restrict__ Bt,
    u16* __restrict__ C, float* __restrict__ Cf, int M, int N, int K,
    const float* __restrict__ bias, const u16* __restrict__ residual, int do_relu)
{
  __shared__ __align__(16) u16 As[128*32];
  __shared__ __align__(16) u16 Bs[128*32];
  int t = threadIdx.x;
  int row0 = blockIdx.y*128, col0 = blockIdx.x*128;
  int l = t&63, w = t>>6;
  int wm = (w>>1)*64, wn = (w&1)*64;
  int lr = l&15, lq = l>>4;
  (void)M;

  f32x4 acc[4][4];
  #pragma unroll
  for (int i=0;i<4;++i)
    #pragma unroll
    for (int j=0;j<4;++j) acc[i][j] = f32x4{0.f,0.f,0.f,0.f};

  const u16* gA = A  + (size_t)(row0 + (t>>2))*K + (t&3)*8;
  const u16* gB = Bt + (size_t)(col0 + (t>>2))*K + (t&3)*8;
  u16* lA = As + t*8;
  u16* lB = Bs + t*8;
  const size_t stride64 = (size_t)64*K;

  for (int k0=0;k0<K;k0+=32){
    async16(gA + k0,            lA);
    async16(gA + stride64 + k0, lA + 2048);
    async16(gB + k0,            lB);
    async16(gB + stride64 + k0, lB + 2048);
    __syncthreads();
    short8 a[4], b[4];
    const u16* pa = As + (wm+lr)*32 + lq*8;
    const u16* pb = Bs + (wn+lr)*32 + lq*8;
    #pragma unroll
    for (int i=0;i<4;++i){ a[i] = *(const short8*)(pa + i*512); b[i] = *(const short8*)(pb + i*512); }
    #pragma unroll
    for (int i=0;i<4;++i)
      #pragma unroll
      for (int j=0;j<4;++j)
        acc[i][j] = __builtin_amdgcn_mfma_f32_16x16x32_bf16(a[i], b[j], acc[i][j], 0,0,0);
    __syncthreads();
  }

  #pragma unroll
  for (int i=0;i<4;++i){
    #pragma unroll
    for (int j=0;j<4;++j){
      int col = col0 + wn + j*16 + lr;
      float bv = bias ? bias[col] : 0.0f;
      #pragma unroll
      for (int r=0;r<4;++r){
        int row = row0 + wm + i*16 + lq*4 + r;
        float v = acc[i][j][r] + bv;
        if (do_relu) v = fmaxf(v, 0.0f);
        if (residual) v += b2f(residual[(size_t)row*N + col]);
        if (Cf) Cf[(size_t)row*N + col] = v;
        else    C [(size_t)row*N + col] = f2b(v);
      }
    }
  }
}

// ---------------- causal flash attention ----------------
// QKV packed [B,T,3072] (q|k|v per head h at col h*64). grid=(T/64, B*H), 4 waves,
// each wave owns 16 q rows. s-tiles of 32, QK^T and PV via mfma 16x16x32.
__global__ __launch_bounds__(256) void attn_kernel(const u16* __restrict__ QKV, u16* __restrict__ O)
{
  const int T=2048, LD=3072, E=1024;
  int qt = blockIdx.x, bh = blockIdx.y;
  int bb = bh>>4, h = bh&15;
  int qbase = qt*64;
  const u16* base = QKV + (size_t)bb*T*LD;
  const u16* Qp = base + h*64;
  const u16* Kp = base + 1024 + h*64;
  const u16* Vp = base + 2048 + h*64;
  int t = threadIdx.x, l = t&63, w = t>>6;
  int lr = l&15, lq = l>>4;

  __shared__ __align__(16) u16 Vt[2][64*40];  // V-tile transposed [hd][32s], ld 40
  __shared__ __align__(16) u16 Pl[4][16*40];  // per-wave P round-trip, ld 40

  int qrow = qbase + w*16 + lr;
  short8 aq0 = *(const short8*)(Qp + (size_t)qrow*LD + lq*8);
  short8 aq1 = *(const short8*)(Qp + (size_t)qrow*LD + 32 + lq*8);

  f32x4 mrun, lrun, Oacc[4];
  #pragma unroll
  for (int r=0;r<4;++r){ mrun[r]=-1e30f; lrun[r]=0.f; }
  #pragma unroll
  for (int n=0;n<4;++n) Oacc[n] = f32x4{0.f,0.f,0.f,0.f};

  const float SCL = 0.125f*1.44269504f;  // 1/sqrt(hd) * log2(e)
  int smax = qbase+63, wqmax = qbase + w*16 + 15;

  for (int s0=0;s0<=smax;s0+=32){
    u16* vt = Vt[(s0>>5)&1];
    { // cooperative transposed V staging
      int sv = t>>3, c0 = (t&7)*8;
      const u16* vp = Vp + (size_t)(s0+sv)*LD + c0;
      ushort4 p0 = *(const ushort4*)(vp);
      ushort4 p1 = *(const ushort4*)(vp+4);
      vt[(c0+0)*40+sv]=p0.x; vt[(c0+1)*40+sv]=p0.y; vt[(c0+2)*40+sv]=p0.z; vt[(c0+3)*40+sv]=p0.w;
      vt[(c0+4)*40+sv]=p1.x; vt[(c0+5)*40+sv]=p1.y; vt[(c0+6)*40+sv]=p1.z; vt[(c0+7)*40+sv]=p1.w;
    }
    __syncthreads();  // single barrier per iter; Vt is double-buffered
    if (s0 <= wqmax){
      f32x4 S[2];
      #pragma unroll
      for (int ss=0;ss<2;++ss){
        const u16* kp = Kp + (size_t)(s0+ss*16+lr)*LD;
        short8 bk0 = *(const short8*)(kp + lq*8);
        short8 bk1 = *(const short8*)(kp + 32 + lq*8);
        f32x4 z = f32x4{0.f,0.f,0.f,0.f};
        z = __builtin_amdgcn_mfma_f32_16x16x32_bf16(aq0, bk0, z, 0,0,0);
        z = __builtin_amdgcn_mfma_f32_16x16x32_bf16(aq1, bk1, z, 0,0,0);
        S[ss]=z;
      }
      #pragma unroll
      for (int ss=0;ss<2;++ss)
        #pragma unroll
        for (int r=0;r<4;++r){
          int sg = s0+ss*16+lr, qg = qbase+w*16+lq*4+r;
          float v = S[ss][r]*SCL;
          S[ss][r] = (sg>qg) ? -1e30f : v;
        }
      f32x4 tm;
      #pragma unroll
      for (int r=0;r<4;++r) tm[r] = fmaxf(S[0][r],S[1][r]);
      #pragma unroll
      for (int off=8;off>=1;off>>=1)
        #pragma unroll
        for (int r=0;r<4;++r) tm[r]=fmaxf(tm[r], __shfl_xor(tm[r],off));
      f32x4 mnew, alpha;
      #pragma unroll
      for (int r=0;r<4;++r){ mnew[r]=fmaxf(mrun[r],tm[r]); alpha[r]=EXP2F(mrun[r]-mnew[r]); }
      #pragma unroll
      for (int ss=0;ss<2;++ss)
        #pragma unroll
        for (int r=0;r<4;++r) S[ss][r]=EXP2F(S[ss][r]-mnew[r]);
      f32x4 ps;
      #pragma unroll
      for (int r=0;r<4;++r) ps[r]=S[0][r]+S[1][r];
      #pragma unroll
      for (int off=8;off>=1;off>>=1)
        #pragma unroll
        for (int r=0;r<4;++r) ps[r]+= __shfl_xor(ps[r],off);
      #pragma unroll
      for (int r=0;r<4;++r){ lrun[r]=lrun[r]*alpha[r]+ps[r]; mrun[r]=mnew[r]; }
      #pragma unroll
      for (int n=0;n<4;++n)
        #pragma unroll
        for (int r=0;r<4;++r) Oacc[n][r]*=alpha[r];
      // P: C-layout -> A-layout via per-wave LDS round-trip
      u16* pw = Pl[w];
      #pragma unroll
      for (int r=0;r<4;++r){
        pw[(lq*4+r)*40 + lr]      = f2b(S[0][r]);
        pw[(lq*4+r)*40 + 16 + lr] = f2b(S[1][r]);
      }
      __asm__ volatile("s_waitcnt lgkmcnt(0)" ::: "memory");
      short8 pf = *(const short8*)(pw + lr*40 + lq*8);
      #pragma unroll
      for (int n=0;n<4;++n){
        short8 vf = *(const short8*)(vt + (n*16+lr)*40 + lq*8);
        Oacc[n] = __builtin_amdgcn_mfma_f32_16x16x32_bf16(pf, vf, Oacc[n], 0,0,0);
      }
    }
  }
  #pragma unroll
  for (int n=0;n<4;++n)
    #pragma unroll
    for (int r=0;r<4;++r){
      int qg = qbase + w*16 + lq*4 + r;
      O[(size_t)(bb*T+qg)*E + h*64 + n*16 + lr] = f2b(Oacc[n][r]/lrun[r]);
    }
}

// ---------------- host ----------------
extern "C" void kernel_launch(void* const* d_in, const int* in_sizes, int n_in,
                              void* d_out, int out_size, void* d_ws, size_t ws_size,
                              hipStream_t stream)
{
  (void)in_sizes; (void)n_in; (void)out_size; (void)ws_size;
  const float* x     = (const float*)d_in[0];
  const float* wq    = (const float*)d_in[1];
  const float* wk    = (const float*)d_in[2];
  const float* wv    = (const float*)d_in[3];
  const float* wproj = (const float*)d_in[4];
  const float* bproj = (const float*)d_in[5];
  const float* g1    = (const float*)d_in[6];
  const float* be1   = (const float*)d_in[7];
  const float* g2    = (const float*)d_in[8];
  const float* be2   = (const float*)d_in[9];
  const float* w1    = (const float*)d_in[10];
  const float* b1    = (const float*)d_in[11];
  const float* w2    = (const float*)d_in[12];
  const float* b2    = (const float*)d_in[13];
  float* out = (float*)d_out;

  char* ws = (char*)d_ws;
  size_t off = 0;
  auto alloc = [&](size_t bytes)->void*{ void* p = ws + off; off += (bytes + 255) & ~(size_t)255; return p; };
  u16* hnorm  = (u16*)alloc((size_t)4096*1024*2);
  u16* qkv    = (u16*)alloc((size_t)4096*3072*2);
  u16* attnO  = (u16*)alloc((size_t)4096*1024*2);
  u16* x2     = (u16*)alloc((size_t)4096*1024*2);
  u16* h2     = (u16*)alloc((size_t)4096*1024*2);
  u16* ffn1   = (u16*)alloc((size_t)4096*4096*2);
  u16* wqkvT  = (u16*)alloc((size_t)3072*1024*2);
  u16* wprojT = (u16*)alloc((size_t)1024*1024*2);
  u16* w1T    = (u16*)alloc((size_t)4096*1024*2);
  u16* w2T    = (u16*)alloc((size_t)1024*4096*2);

  // weight repacks (fp32 -> bf16, transposed for Bt-layout GEMM)
  qkv_repack  <<<dim3(16,48),256,0,stream>>>(wq,wk,wv,wqkvT);
  transpose_bt<<<dim3(16,16),256,0,stream>>>(wproj, wprojT, 1024, 1024);
  transpose_bt<<<dim3(64,16),256,0,stream>>>(w1,    w1T,    4096, 1024);
  transpose_bt<<<dim3(16,64),256,0,stream>>>(w2,    w2T,    1024, 4096);

  // h = LN(x)*g1+b1   (fp32 in, bf16 out)
  ln_kernel<1><<<4096,256,0,stream>>>(x, g1, be1, hnorm);
  // QKV = h @ [Wq|Wk|Wv]
  gemm_bt<<<dim3(24,32),256,0,stream>>>(hnorm, wqkvT, qkv, nullptr, 4096,3072,1024, nullptr, nullptr, 0);
  // causal attention
  attn_kernel<<<dim3(32,32),256,0,stream>>>(qkv, attnO);
  // x2 = h + (attnO @ Wproj + bproj)
  gemm_bt<<<dim3(8,32),256,0,stream>>>(attnO, wprojT, x2, nullptr, 4096,1024,1024, bproj, hnorm, 0);
  // h2 = LN(x2)*g2+b2  (bf16 in, bf16 out)
  ln_kernel<0><<<4096,256,0,stream>>>(x2, g2, be2, h2);
  // ffn1 = relu(h2 @ W1 + b1)
  gemm_bt<<<dim3(32,32),256,0,stream>>>(h2, w1T, ffn1, nullptr, 4096,4096,1024, b1, nullptr, 1);
  // out = h2 + (ffn1 @ W2 + b2)   (fp32 output)
  gemm_bt<<<dim3(8,32),256,0,stream>>>(ffn1, w2T, nullptr, out, 4096,1024,4096, b2, h2, 0);
}

// Round 3
// 471.721 us; speedup vs baseline: 1.2589x; 1.2589x over previous
//
#include <hip/hip_runtime.h>
#include <stdint.h>

typedef unsigned short u16;
typedef __attribute__((ext_vector_type(8))) short short8;
typedef __attribute__((ext_vector_type(4))) short short4_t;
typedef __attribute__((ext_vector_type(4))) float f32x4;

__device__ __forceinline__ float b2f(u16 u){ union{unsigned i; float f;}v; v.i=((unsigned)u)<<16; return v.f; }
__device__ __forceinline__ u16 f2b(float f){ unsigned x=__float_as_uint(f); return (u16)((x + 0x7fffu + ((x>>16)&1u))>>16); }

#if __has_builtin(__builtin_amdgcn_exp2f)
#define EXP2F(x) __builtin_amdgcn_exp2f(x)
#else
#define EXP2F(x) exp2f(x)
#endif

__device__ __forceinline__ void async16(const void* g, void* l){
  __builtin_amdgcn_global_load_lds((const __attribute__((address_space(1))) void*)g,
                                   (__attribute__((address_space(3))) void*)l, 16, 0, 0);
}

// ---------------- LayerNorm (E=1024, one block per row) ----------------
template<int IN_F32>
__global__ __launch_bounds__(256) void ln_kernel(const void* __restrict__ xin,
    const float* __restrict__ g, const float* __restrict__ b, u16* __restrict__ y)
{
  const int E = 1024;
  int row = blockIdx.x, t = threadIdx.x;
  float f0,f1,f2,f3;
  if (IN_F32){
    const float* xr = (const float*)xin + (size_t)row*E;
    float4 xv = *(const float4*)(xr + t*4);
    f0=xv.x; f1=xv.y; f2=xv.z; f3=xv.w;
  } else {
    const u16* xr = (const u16*)xin + (size_t)row*E;
    ushort4 xv = *(const ushort4*)(xr + t*4);
    f0=b2f(xv.x); f1=b2f(xv.y); f2=b2f(xv.z); f3=b2f(xv.w);
  }
  float s1 = f0+f1+f2+f3;
  float s2 = f0*f0+f1*f1+f2*f2+f3*f3;
  #pragma unroll
  for (int off=32; off>=1; off>>=1){ s1 += __shfl_xor(s1,off); s2 += __shfl_xor(s2,off); }
  __shared__ float red[8];
  int w = t>>6;
  if ((t&63)==0){ red[w]=s1; red[4+w]=s2; }
  __syncthreads();
  float S1 = red[0]+red[1]+red[2]+red[3];
  float S2 = red[4]+red[5]+red[6]+red[7];
  float mean = S1*(1.0f/E);
  float var  = S2*(1.0f/E) - mean*mean;
  float inv  = rsqrtf(var + 1e-5f);
  float4 gv = *(const float4*)(g + t*4);
  float4 bv = *(const float4*)(b + t*4);
  ushort4 o;
  o.x = f2b((f0-mean)*inv*gv.x+bv.x);
  o.y = f2b((f1-mean)*inv*gv.y+bv.y);
  o.z = f2b((f2-mean)*inv*gv.z+bv.z);
  o.w = f2b((f3-mean)*inv*gv.w+bv.w);
  *(ushort4*)(y + (size_t)row*E + t*4) = o;
}

// ---------------- fp32->bf16 64x64-tiled transpose ----------------
__global__ __launch_bounds__(256) void transpose_bt(const float* __restrict__ src, u16* __restrict__ dst,
                                                    int ld_src, int ld_dst)
{
  __shared__ u16 tile[64*66];
  int c0 = blockIdx.x*64, r0 = blockIdx.y*64;
  int t = threadIdx.x;
  #pragma unroll
  for (int i=0;i<16;++i){
    int lin = i*256 + t;
    int rr = lin>>6, cc = lin&63;
    tile[cc*66+rr] = f2b(src[(size_t)(r0+rr)*ld_src + c0+cc]);
  }
  __syncthreads();
  #pragma unroll
  for (int i=0;i<16;++i){
    int lin = i*256 + t;
    int cc = lin>>6, rr = lin&63;
    dst[(size_t)(c0+cc)*ld_dst + r0+rr] = tile[cc*66+rr];
  }
}

// ---------------- QKV weight repack ----------------
__global__ __launch_bounds__(256) void qkv_repack(const float* __restrict__ wq, const float* __restrict__ wk,
                                                  const float* __restrict__ wv, u16* __restrict__ dst)
{
  __shared__ u16 tile[64*66];
  int e0 = blockIdx.x*64;
  int sel = blockIdx.y>>4, h = blockIdx.y&15;
  const float* src = (sel==0?wq:(sel==1?wk:wv)) + (size_t)h*1024*64;
  int t = threadIdx.x;
  #pragma unroll
  for (int i=0;i<16;++i){
    int lin=i*256+t; int rr=lin>>6, cc=lin&63;
    tile[cc*66+rr] = f2b(src[(size_t)(e0+rr)*64 + cc]);
  }
  __syncthreads();
  #pragma unroll
  for (int i=0;i<16;++i){
    int lin=i*256+t; int cc=lin>>6, rr=lin&63;
    dst[(size_t)(sel*1024 + h*64 + cc)*1024 + e0+rr] = tile[cc*66+rr];
  }
}

// ---------------- m97-style bf16 GEMM ----------------
__global__ __launch_bounds__(256) void gemm_bt(const u16* __restrict__ A, const u16* __restrict__ Bt,
    u16* __restrict__ C, float* __restrict__ Cf, int M, int N, int K,
    const float* __restrict__ bias, const u16* __restrict__ residual, int do_relu)
{
  __shared__ __align__(16) u16 As[128*32];
  __shared__ __align__(16) u16 Bs[128*32];
  int t = threadIdx.x;
  int row0 = blockIdx.y*128, col0 = blockIdx.x*128;
  int l = t&63, w = t>>6;
  int wm = (w>>1)*64, wn = (w&1)*64;
  int lr = l&15, lq = l>>4;
  (void)M;

  f32x4 acc[4][4];
  #pragma unroll
  for (int i=0;i<4;++i)
    #pragma unroll
    for (int j=0;j<4;++j) acc[i][j] = f32x4{0.f,0.f,0.f,0.f};

  const u16* gA = A  + (size_t)(row0 + (t>>2))*K + (t&3)*8;
  const u16* gB = Bt + (size_t)(col0 + (t>>2))*K + (t&3)*8;
  u16* lA = As + t*8;
  u16* lB = Bs + t*8;
  const size_t stride64 = (size_t)64*K;

  for (int k0=0;k0<K;k0+=32){
    async16(gA + k0,            lA);
    async16(gA + stride64 + k0, lA + 2048);
    async16(gB + k0,            lB);
    async16(gB + stride64 + k0, lB + 2048);
    __syncthreads();
    short8 a[4], b[4];
    const u16* pa = As + (wm+lr)*32 + lq*8;
    const u16* pb = Bs + (wn+lr)*32 + lq*8;
    #pragma unroll
    for (int i=0;i<4;++i){ a[i] = *(const short8*)(pa + i*512); b[i] = *(const short8*)(pb + i*512); }
    #pragma unroll
    for (int i=0;i<4;++i)
      #pragma unroll
      for (int j=0;j<4;++j)
        acc[i][j] = __builtin_amdgcn_mfma_f32_16x16x32_bf16(a[i], b[j], acc[i][j], 0,0,0);
    __syncthreads();
  }

  #pragma unroll
  for (int i=0;i<4;++i){
    #pragma unroll
    for (int j=0;j<4;++j){
      int col = col0 + wn + j*16 + lr;
      float bv = bias ? bias[col] : 0.0f;
      #pragma unroll
      for (int r=0;r<4;++r){
        int row = row0 + wm + i*16 + lq*4 + r;
        float v = acc[i][j][r] + bv;
        if (do_relu) v = fmaxf(v, 0.0f);
        if (residual) v += b2f(residual[(size_t)row*N + col]);
        if (Cf) Cf[(size_t)row*N + col] = v;
        else    C [(size_t)row*N + col] = f2b(v);
      }
    }
  }
}

// ---------------- causal flash attention v2 ----------------
// Q-tile 128 (wave=32 q rows), s-tile 64. S^T = op(K,Q) so softmax reduces
// with 2 shuffles and P packs to b64 LDS writes / b128 reads. K staged via
// swizzled global_load_lds; V staged transposed. grid=(16, B*H), heavy-first.
__global__ __launch_bounds__(256) void attn_kernel(const u16* __restrict__ QKV, u16* __restrict__ O)
{
  const int T=2048, LD=3072, E=1024;
  int qt = 15 - blockIdx.x;
  int bh = blockIdx.y, bb = bh>>4, h = bh&15;
  int qbase = qt*128;
  const u16* base = QKV + (size_t)bb*T*LD;
  const u16* Qp = base + h*64;
  const u16* Kp = base + 1024 + h*64;
  const u16* Vp = base + 2048 + h*64;
  int t = threadIdx.x, l = t&63, w = t>>6;
  int lr = l&15, lq = l>>4;

  __shared__ __align__(16) u16 Ks[64*64];      // [s][hd], chunk c stored at c^(s&7)
  __shared__ __align__(16) u16 Vt[64*72];      // [d][s], ld 72
  __shared__ __align__(16) u16 Pb[4][32*72];   // per-wave P [q][s], ld 72

  const float QSC = 0.125f*1.44269504f;        // 1/sqrt(64) * log2(e)
  short8 aq[2][2];
  #pragma unroll
  for (int qf=0;qf<2;++qf)
    #pragma unroll
    for (int kk=0;kk<2;++kk){
      const u16* qp = Qp + (size_t)(qbase + w*32 + qf*16 + lr)*LD + kk*32 + lq*8;
      short8 raw = *(const short8*)qp;
      short8 sc;
      #pragma unroll
      for (int j=0;j<8;++j) sc[j] = (short)f2b(b2f((u16)raw[j])*QSC);
      aq[qf][kk]=sc;
    }

  float mrun[2] = {-3e38f,-3e38f}, lrun[2] = {0.f,0.f};
  f32x4 Oacc[2][4];
  #pragma unroll
  for (int qf=0;qf<2;++qf)
    #pragma unroll
    for (int dt=0;dt<4;++dt) Oacc[qf][dt] = f32x4{0.f,0.f,0.f,0.f};

  int kc = (l&7) ^ (l>>3);           // K chunk swizzle
  int s_a = 8*w + (l>>3);            // K staging rows
  int sv = (l&31)*2;                 // V staging rows (pair)
  int vc0 = (t>>5)*8;                // V staging chunk
  int qw0 = qbase + w*32;

  int nIter = 2*qt + 2;
  for (int it=0; it<nIter; ++it){
    int s0 = it*64;
    __syncthreads();  // prior compute done before restaging
    // --- K stage (global_load_lds, swizzled) ---
    async16(Kp + (size_t)(s0+s_a)*LD    + kc*8, Ks + ((size_t)w*64       + l)*8);
    async16(Kp + (size_t)(s0+s_a+32)*LD + kc*8, Ks + ((size_t)(4+w)*64   + l)*8);
    // --- V stage (transposed, paired b32 writes) ---
    {
      const u16* vp0 = Vp + (size_t)(s0+sv)*LD + vc0;
      ushort4 a0 = *(const ushort4*)vp0;
      ushort4 a1 = *(const ushort4*)(vp0+4);
      ushort4 b0 = *(const ushort4*)(vp0+LD);
      ushort4 b1 = *(const ushort4*)(vp0+LD+4);
      u16 av[8] = {a0.x,a0.y,a0.z,a0.w,a1.x,a1.y,a1.z,a1.w};
      u16 bv[8] = {b0.x,b0.y,b0.z,b0.w,b1.x,b1.y,b1.z,b1.w};
      #pragma unroll
      for (int kth=0;kth<8;++kth)
        *(uint*)(Vt + (size_t)(vc0+kth)*72 + sv) = (uint)av[kth] | ((uint)bv[kth]<<16);
    }
    __syncthreads();
    if (s0 <= qw0 + 31){
      bool need_mask = (s0 + 63 > qw0);
      f32x4 S[2][4];
      #pragma unroll
      for (int st=0; st<4; ++st){
        short8 kf0 = *(const short8*)(Ks + (st*16+lr)*64 + ((lq  )^(lr&7))*8);
        short8 kf1 = *(const short8*)(Ks + (st*16+lr)*64 + ((4+lq)^(lr&7))*8);
        #pragma unroll
        for (int qf=0;qf<2;++qf){
          f32x4 z = f32x4{0.f,0.f,0.f,0.f};
          z = __builtin_amdgcn_mfma_f32_16x16x32_bf16(kf0, aq[qf][0], z, 0,0,0);
          z = __builtin_amdgcn_mfma_f32_16x16x32_bf16(kf1, aq[qf][1], z, 0,0,0);
          S[qf][st] = z;
        }
      }
      if (need_mask){
        #pragma unroll
        for (int qf=0;qf<2;++qf){
          int qg = qw0 + qf*16 + lr;
          #pragma unroll
          for (int st=0;st<4;++st)
            #pragma unroll
            for (int r=0;r<4;++r){
              int sg = s0 + st*16 + lq*4 + r;
              if (sg > qg) S[qf][st][r] = -3e38f;
            }
        }
      }
      #pragma unroll
      for (int qf=0;qf<2;++qf){
        float m01 = fmaxf(fmaxf(S[qf][0][0],S[qf][0][1]),fmaxf(S[qf][0][2],S[qf][0][3]));
        float m11 = fmaxf(fmaxf(S[qf][1][0],S[qf][1][1]),fmaxf(S[qf][1][2],S[qf][1][3]));
        float m21 = fmaxf(fmaxf(S[qf][2][0],S[qf][2][1]),fmaxf(S[qf][2][2],S[qf][2][3]));
        float m31 = fmaxf(fmaxf(S[qf][3][0],S[qf][3][1]),fmaxf(S[qf][3][2],S[qf][3][3]));
        float m = fmaxf(fmaxf(m01,m11),fmaxf(m21,m31));
        m = fmaxf(m, __shfl_xor(m,16));
        m = fmaxf(m, __shfl_xor(m,32));
        float mnew = fmaxf(mrun[qf], m);
        float alpha = EXP2F(mrun[qf]-mnew);
        mrun[qf] = mnew;
        float ssum = 0.f;
        #pragma unroll
        for (int st=0;st<4;++st)
          #pragma unroll
          for (int r=0;r<4;++r){ float p = EXP2F(S[qf][st][r]-mnew); S[qf][st][r]=p; ssum+=p; }
        ssum += __shfl_xor(ssum,16);
        ssum += __shfl_xor(ssum,32);
        lrun[qf] = lrun[qf]*alpha + ssum;
        u16* pb = Pb[w] + (qf*16+lr)*72;
        #pragma unroll
        for (int st=0;st<4;++st){
          short4_t pk;
          pk.x=(short)f2b(S[qf][st][0]); pk.y=(short)f2b(S[qf][st][1]);
          pk.z=(short)f2b(S[qf][st][2]); pk.w=(short)f2b(S[qf][st][3]);
          *(short4_t*)(pb + st*16 + lq*4) = pk;
        }
        float af[4];
        #pragma unroll
        for (int r=0;r<4;++r) af[r] = __shfl(alpha, lq*4+r);
        #pragma unroll
        for (int dt=0;dt<4;++dt)
          #pragma unroll
          for (int r=0;r<4;++r) Oacc[qf][dt][r] *= af[r];
      }
      __asm__ volatile("s_waitcnt lgkmcnt(0)" ::: "memory");
      #pragma unroll
      for (int kk=0;kk<2;++kk){
        short8 pf0 = *(const short8*)(Pb[w] + (lr   )*72 + kk*32 + lq*8);
        short8 pf1 = *(const short8*)(Pb[w] + (16+lr)*72 + kk*32 + lq*8);
        #pragma unroll
        for (int dt=0;dt<4;++dt){
          short8 vf = *(const short8*)(Vt + (dt*16+lr)*72 + kk*32 + lq*8);
          Oacc[0][dt] = __builtin_amdgcn_mfma_f32_16x16x32_bf16(pf0, vf, Oacc[0][dt], 0,0,0);
          Oacc[1][dt] = __builtin_amdgcn_mfma_f32_16x16x32_bf16(pf1, vf, Oacc[1][dt], 0,0,0);
        }
      }
    }
  }
  float linv[2][4];
  #pragma unroll
  for (int qf=0;qf<2;++qf)
    #pragma unroll
    for (int r=0;r<4;++r) linv[qf][r] = 1.0f/__shfl(lrun[qf], lq*4+r);
  #pragma unroll
  for (int qf=0;qf<2;++qf)
    #pragma unroll
    for (int dt=0;dt<4;++dt)
      #pragma unroll
      for (int r=0;r<4;++r){
        int qg = qbase + w*32 + qf*16 + lq*4 + r;
        O[(size_t)(bb*T+qg)*E + h*64 + dt*16 + lr] = f2b(Oacc[qf][dt][r]*linv[qf][r]);
      }
}

// ---------------- host ----------------
extern "C" void kernel_launch(void* const* d_in, const int* in_sizes, int n_in,
                              void* d_out, int out_size, void* d_ws, size_t ws_size,
                              hipStream_t stream)
{
  (void)in_sizes; (void)n_in; (void)out_size; (void)ws_size;
  const float* x     = (const float*)d_in[0];
  const float* wq    = (const float*)d_in[1];
  const float* wk    = (const float*)d_in[2];
  const float* wv    = (const float*)d_in[3];
  const float* wproj = (const float*)d_in[4];
  const float* bproj = (const float*)d_in[5];
  const float* g1    = (const float*)d_in[6];
  const float* be1   = (const float*)d_in[7];
  const float* g2    = (const float*)d_in[8];
  const float* be2   = (const float*)d_in[9];
  const float* w1    = (const float*)d_in[10];
  const float* b1    = (const float*)d_in[11];
  const float* w2    = (const float*)d_in[12];
  const float* b2    = (const float*)d_in[13];
  float* out = (float*)d_out;

  char* ws = (char*)d_ws;
  size_t off = 0;
  auto alloc = [&](size_t bytes)->void*{ void* p = ws + off; off += (bytes + 255) & ~(size_t)255; return p; };
  u16* hnorm  = (u16*)alloc((size_t)4096*1024*2);
  u16* qkv    = (u16*)alloc((size_t)4096*3072*2);
  u16* attnO  = (u16*)alloc((size_t)4096*1024*2);
  u16* x2     = (u16*)alloc((size_t)4096*1024*2);
  u16* h2     = (u16*)alloc((size_t)4096*1024*2);
  u16* ffn1   = (u16*)alloc((size_t)4096*4096*2);
  u16* wqkvT  = (u16*)alloc((size_t)3072*1024*2);
  u16* wprojT = (u16*)alloc((size_t)1024*1024*2);
  u16* w1T    = (u16*)alloc((size_t)4096*1024*2);
  u16* w2T    = (u16*)alloc((size_t)1024*4096*2);

  qkv_repack  <<<dim3(16,48),256,0,stream>>>(wq,wk,wv,wqkvT);
  transpose_bt<<<dim3(16,16),256,0,stream>>>(wproj, wprojT, 1024, 1024);
  transpose_bt<<<dim3(64,16),256,0,stream>>>(w1,    w1T,    4096, 1024);
  transpose_bt<<<dim3(16,64),256,0,stream>>>(w2,    w2T,    1024, 4096);

  ln_kernel<1><<<4096,256,0,stream>>>(x, g1, be1, hnorm);
  gemm_bt<<<dim3(24,32),256,0,stream>>>(hnorm, wqkvT, qkv, nullptr, 4096,3072,1024, nullptr, nullptr, 0);
  attn_kernel<<<dim3(16,32),256,0,stream>>>(qkv, attnO);
  gemm_bt<<<dim3(8,32),256,0,stream>>>(attnO, wprojT, x2, nullptr, 4096,1024,1024, bproj, hnorm, 0);
  ln_kernel<0><<<4096,256,0,stream>>>(x2, g2, be2, h2);
  gemm_bt<<<dim3(32,32),256,0,stream>>>(h2, w1T, ffn1, nullptr, 4096,4096,1024, b1, nullptr, 1);
  gemm_bt<<<dim3(8,32),256,0,stream>>>(ffn1, w2T, nullptr, out, 4096,1024,4096, b2, h2, 0);
}

// Round 4
// 430.653 us; speedup vs baseline: 1.3789x; 1.0954x over previous
//
#include <hip/hip_runtime.h>
#include <stdint.h>

typedef unsigned short u16;
typedef __attribute__((ext_vector_type(8))) short short8;
typedef __attribute__((ext_vector_type(4))) short short4_t;
typedef __attribute__((ext_vector_type(4))) float f32x4;

__device__ __forceinline__ float b2f(u16 u){ union{unsigned i; float f;}v; v.i=((unsigned)u)<<16; return v.f; }
__device__ __forceinline__ u16 f2b(float f){ unsigned x=__float_as_uint(f); return (u16)((x + 0x7fffu + ((x>>16)&1u))>>16); }

#if __has_builtin(__builtin_amdgcn_exp2f)
#define EXP2F(x) __builtin_amdgcn_exp2f(x)
#else
#define EXP2F(x) exp2f(x)
#endif

__device__ __forceinline__ void async16(const void* g, void* l){
  __builtin_amdgcn_global_load_lds((const __attribute__((address_space(1))) void*)g,
                                   (__attribute__((address_space(3))) void*)l, 16, 0, 0);
}

// ---------------- LayerNorm (E=1024, one block per row) ----------------
template<int IN_F32>
__global__ __launch_bounds__(256) void ln_kernel(const void* __restrict__ xin,
    const float* __restrict__ g, const float* __restrict__ b, u16* __restrict__ y)
{
  const int E = 1024;
  int row = blockIdx.x, t = threadIdx.x;
  float f0,f1,f2,f3;
  if (IN_F32){
    const float* xr = (const float*)xin + (size_t)row*E;
    float4 xv = *(const float4*)(xr + t*4);
    f0=xv.x; f1=xv.y; f2=xv.z; f3=xv.w;
  } else {
    const u16* xr = (const u16*)xin + (size_t)row*E;
    ushort4 xv = *(const ushort4*)(xr + t*4);
    f0=b2f(xv.x); f1=b2f(xv.y); f2=b2f(xv.z); f3=b2f(xv.w);
  }
  float s1 = f0+f1+f2+f3;
  float s2 = f0*f0+f1*f1+f2*f2+f3*f3;
  #pragma unroll
  for (int off=32; off>=1; off>>=1){ s1 += __shfl_xor(s1,off); s2 += __shfl_xor(s2,off); }
  __shared__ float red[8];
  int w = t>>6;
  if ((t&63)==0){ red[w]=s1; red[4+w]=s2; }
  __syncthreads();
  float S1 = red[0]+red[1]+red[2]+red[3];
  float S2 = red[4]+red[5]+red[6]+red[7];
  float mean = S1*(1.0f/E);
  float var  = S2*(1.0f/E) - mean*mean;
  float inv  = rsqrtf(var + 1e-5f);
  float4 gv = *(const float4*)(g + t*4);
  float4 bv = *(const float4*)(b + t*4);
  ushort4 o;
  o.x = f2b((f0-mean)*inv*gv.x+bv.x);
  o.y = f2b((f1-mean)*inv*gv.y+bv.y);
  o.z = f2b((f2-mean)*inv*gv.z+bv.z);
  o.w = f2b((f3-mean)*inv*gv.w+bv.w);
  *(ushort4*)(y + (size_t)row*E + t*4) = o;
}

// ---------------- fp32->bf16 64x64-tiled transpose ----------------
__global__ __launch_bounds__(256) void transpose_bt(const float* __restrict__ src, u16* __restrict__ dst,
                                                    int ld_src, int ld_dst)
{
  __shared__ u16 tile[64*66];
  int c0 = blockIdx.x*64, r0 = blockIdx.y*64;
  int t = threadIdx.x;
  #pragma unroll
  for (int i=0;i<16;++i){
    int lin = i*256 + t;
    int rr = lin>>6, cc = lin&63;
    tile[cc*66+rr] = f2b(src[(size_t)(r0+rr)*ld_src + c0+cc]);
  }
  __syncthreads();
  #pragma unroll
  for (int i=0;i<16;++i){
    int lin = i*256 + t;
    int cc = lin>>6, rr = lin&63;
    dst[(size_t)(c0+cc)*ld_dst + r0+rr] = tile[cc*66+rr];
  }
}

// ---------------- QKV weight repack ----------------
__global__ __launch_bounds__(256) void qkv_repack(const float* __restrict__ wq, const float* __restrict__ wk,
                                                  const float* __restrict__ wv, u16* __restrict__ dst)
{
  __shared__ u16 tile[64*66];
  int e0 = blockIdx.x*64;
  int sel = blockIdx.y>>4, h = blockIdx.y&15;
  const float* src = (sel==0?wq:(sel==1?wk:wv)) + (size_t)h*1024*64;
  int t = threadIdx.x;
  #pragma unroll
  for (int i=0;i<16;++i){
    int lin=i*256+t; int rr=lin>>6, cc=lin&63;
    tile[cc*66+rr] = f2b(src[(size_t)(e0+rr)*64 + cc]);
  }
  __syncthreads();
  #pragma unroll
  for (int i=0;i<16;++i){
    int lin=i*256+t; int cc=lin>>6, rr=lin&63;
    dst[(size_t)(sel*1024 + h*64 + cc)*1024 + e0+rr] = tile[cc*66+rr];
  }
}

// ---------------- bf16 GEMM: C[M][N] = A[M][K] * Bt[N][K]^T ----------------
// 128x128 tile, 4 waves, mfma 16x16x32, double-buffered LDS with
// global_load_lds width-16 prefetch (1 barrier/iter), XCD-compact swizzle.
__global__ __launch_bounds__(256,2) void gemm_bt(const u16* __restrict__ A, const u16* __restrict__ Bt,
    u16* __restrict__ C, float* __restrict__ Cf, int M, int N, int K,
    const float* __restrict__ bias, const u16* __restrict__ residual, int do_relu, int gx)
{
  __shared__ __align__(16) u16 As[2][128*32];
  __shared__ __align__(16) u16 Bs[2][128*32];
  int t = threadIdx.x;
  // XCD-compact swizzle: xcd = bid&7 owns a (gridDim.x/gx) x (gridDim.y/(8/gx))
  // sub-rectangle, cols-fastest so concurrent blocks share strips in L2.
  int bid = blockIdx.y * gridDim.x + blockIdx.x;
  int xcd = bid & 7, slot = bid >> 3;
  int gy = 8 / gx;
  int rx = gridDim.x / gx, ry = gridDim.y / gy;
  int col_b = (xcd % gx) * rx + (slot % rx);
  int row_b = (xcd / gx) * ry + (slot / rx);
  int row0 = row_b*128, col0 = col_b*128;
  int l = t&63, w = t>>6;
  int wm = (w>>1)*64, wn = (w&1)*64;
  int lr = l&15, lq = l>>4;
  (void)M;

  f32x4 acc[4][4];
  #pragma unroll
  for (int i=0;i<4;++i)
    #pragma unroll
    for (int j=0;j<4;++j) acc[i][j] = f32x4{0.f,0.f,0.f,0.f};

  const u16* gA = A  + (size_t)(row0 + (t>>2))*K + (t&3)*8;
  const u16* gB = Bt + (size_t)(col0 + (t>>2))*K + (t&3)*8;
  const size_t stride64 = (size_t)64*K;
  int nk = K>>5;

  // prologue: prefetch tile 0 into buffer 0
  {
    u16* dA = As[0] + t*8; u16* dB = Bs[0] + t*8;
    async16(gA,            dA);
    async16(gA + stride64, dA + 2048);
    async16(gB,            dB);
    async16(gB + stride64, dB + 2048);
  }

  for (int kt=0; kt<nk; ++kt){
    int cur = kt&1;
    __syncthreads();   // drains prefetch for 'cur'; guards reuse of 'cur^1'
    if (kt+1 < nk){
      int ko = (kt+1)<<5;
      u16* dA = As[cur^1] + t*8; u16* dB = Bs[cur^1] + t*8;
      async16(gA + ko,            dA);
      async16(gA + stride64 + ko, dA + 2048);
      async16(gB + ko,            dB);
      async16(gB + stride64 + ko, dB + 2048);
    }
    short8 a[4], b[4];
    const u16* pa = As[cur] + (wm+lr)*32 + lq*8;
    const u16* pb = Bs[cur] + (wn+lr)*32 + lq*8;
    #pragma unroll
    for (int i=0;i<4;++i){ a[i] = *(const short8*)(pa + i*512); b[i] = *(const short8*)(pb + i*512); }
    #pragma unroll
    for (int i=0;i<4;++i)
      #pragma unroll
      for (int j=0;j<4;++j)
        acc[i][j] = __builtin_amdgcn_mfma_f32_16x16x32_bf16(a[i], b[j], acc[i][j], 0,0,0);
  }

  #pragma unroll
  for (int i=0;i<4;++i){
    #pragma unroll
    for (int j=0;j<4;++j){
      int col = col0 + wn + j*16 + lr;
      float bv = bias ? bias[col] : 0.0f;
      #pragma unroll
      for (int r=0;r<4;++r){
        int row = row0 + wm + i*16 + lq*4 + r;
        float v = acc[i][j][r] + bv;
        if (do_relu) v = fmaxf(v, 0.0f);
        if (residual) v += b2f(residual[(size_t)row*N + col]);
        if (Cf) Cf[(size_t)row*N + col] = v;
        else    C [(size_t)row*N + col] = f2b(v);
      }
    }
  }
}

// ---------------- causal flash attention v2 (XCD-swizzled) ----------------
__global__ __launch_bounds__(256) void attn_kernel(const u16* __restrict__ QKV, u16* __restrict__ O)
{
  const int T=2048, LD=3072, E=1024;
  // swizzle: each XCD owns 4 bh's (KV set ~2MB), q-tiles heavy-first within.
  int bid = blockIdx.y * gridDim.x + blockIdx.x;
  int xcd = bid & 7, slot = bid >> 3;
  int qt = 15 - (slot & 15);
  int bh = xcd*4 + (slot >> 4);
  int bb = bh>>4, h = bh&15;
  int qbase = qt*128;
  const u16* base = QKV + (size_t)bb*T*LD;
  const u16* Qp = base + h*64;
  const u16* Kp = base + 1024 + h*64;
  const u16* Vp = base + 2048 + h*64;
  int t = threadIdx.x, l = t&63, w = t>>6;
  int lr = l&15, lq = l>>4;

  __shared__ __align__(16) u16 Ks[64*64];      // [s][hd], chunk c stored at c^(s&7)
  __shared__ __align__(16) u16 Vt[64*72];      // [d][s], ld 72
  __shared__ __align__(16) u16 Pb[4][32*72];   // per-wave P [q][s], ld 72

  const float QSC = 0.125f*1.44269504f;        // 1/sqrt(64) * log2(e)
  short8 aq[2][2];
  #pragma unroll
  for (int qf=0;qf<2;++qf)
    #pragma unroll
    for (int kk=0;kk<2;++kk){
      const u16* qp = Qp + (size_t)(qbase + w*32 + qf*16 + lr)*LD + kk*32 + lq*8;
      short8 raw = *(const short8*)qp;
      short8 sc;
      #pragma unroll
      for (int j=0;j<8;++j) sc[j] = (short)f2b(b2f((u16)raw[j])*QSC);
      aq[qf][kk]=sc;
    }

  float mrun[2] = {-3e38f,-3e38f}, lrun[2] = {0.f,0.f};
  f32x4 Oacc[2][4];
  #pragma unroll
  for (int qf=0;qf<2;++qf)
    #pragma unroll
    for (int dt=0;dt<4;++dt) Oacc[qf][dt] = f32x4{0.f,0.f,0.f,0.f};

  int kc = (l&7) ^ (l>>3);           // K chunk swizzle
  int s_a = 8*w + (l>>3);            // K staging rows
  int sv = (l&31)*2;                 // V staging rows (pair)
  int vc0 = (t>>5)*8;                // V staging chunk
  int qw0 = qbase + w*32;

  int nIter = 2*qt + 2;
  for (int it=0; it<nIter; ++it){
    int s0 = it*64;
    __syncthreads();
    async16(Kp + (size_t)(s0+s_a)*LD    + kc*8, Ks + ((size_t)w*64       + l)*8);
    async16(Kp + (size_t)(s0+s_a+32)*LD + kc*8, Ks + ((size_t)(4+w)*64   + l)*8);
    {
      const u16* vp0 = Vp + (size_t)(s0+sv)*LD + vc0;
      ushort4 a0 = *(const ushort4*)vp0;
      ushort4 a1 = *(const ushort4*)(vp0+4);
      ushort4 b0 = *(const ushort4*)(vp0+LD);
      ushort4 b1 = *(const ushort4*)(vp0+LD+4);
      u16 av[8] = {a0.x,a0.y,a0.z,a0.w,a1.x,a1.y,a1.z,a1.w};
      u16 bv[8] = {b0.x,b0.y,b0.z,b0.w,b1.x,b1.y,b1.z,b1.w};
      #pragma unroll
      for (int kth=0;kth<8;++kth)
        *(uint*)(Vt + (size_t)(vc0+kth)*72 + sv) = (uint)av[kth] | ((uint)bv[kth]<<16);
    }
    __syncthreads();
    if (s0 <= qw0 + 31){
      bool need_mask = (s0 + 63 > qw0);
      f32x4 S[2][4];
      #pragma unroll
      for (int st=0; st<4; ++st){
        short8 kf0 = *(const short8*)(Ks + (st*16+lr)*64 + ((lq  )^(lr&7))*8);
        short8 kf1 = *(const short8*)(Ks + (st*16+lr)*64 + ((4+lq)^(lr&7))*8);
        #pragma unroll
        for (int qf=0;qf<2;++qf){
          f32x4 z = f32x4{0.f,0.f,0.f,0.f};
          z = __builtin_amdgcn_mfma_f32_16x16x32_bf16(kf0, aq[qf][0], z, 0,0,0);
          z = __builtin_amdgcn_mfma_f32_16x16x32_bf16(kf1, aq[qf][1], z, 0,0,0);
          S[qf][st] = z;
        }
      }
      if (need_mask){
        #pragma unroll
        for (int qf=0;qf<2;++qf){
          int qg = qw0 + qf*16 + lr;
          #pragma unroll
          for (int st=0;st<4;++st)
            #pragma unroll
            for (int r=0;r<4;++r){
              int sg = s0 + st*16 + lq*4 + r;
              if (sg > qg) S[qf][st][r] = -3e38f;
            }
        }
      }
      #pragma unroll
      for (int qf=0;qf<2;++qf){
        float m01 = fmaxf(fmaxf(S[qf][0][0],S[qf][0][1]),fmaxf(S[qf][0][2],S[qf][0][3]));
        float m11 = fmaxf(fmaxf(S[qf][1][0],S[qf][1][1]),fmaxf(S[qf][1][2],S[qf][1][3]));
        float m21 = fmaxf(fmaxf(S[qf][2][0],S[qf][2][1]),fmaxf(S[qf][2][2],S[qf][2][3]));
        float m31 = fmaxf(fmaxf(S[qf][3][0],S[qf][3][1]),fmaxf(S[qf][3][2],S[qf][3][3]));
        float m = fmaxf(fmaxf(m01,m11),fmaxf(m21,m31));
        m = fmaxf(m, __shfl_xor(m,16));
        m = fmaxf(m, __shfl_xor(m,32));
        float mnew = fmaxf(mrun[qf], m);
        float alpha = EXP2F(mrun[qf]-mnew);
        mrun[qf] = mnew;
        float ssum = 0.f;
        #pragma unroll
        for (int st=0;st<4;++st)
          #pragma unroll
          for (int r=0;r<4;++r){ float p = EXP2F(S[qf][st][r]-mnew); S[qf][st][r]=p; ssum+=p; }
        ssum += __shfl_xor(ssum,16);
        ssum += __shfl_xor(ssum,32);
        lrun[qf] = lrun[qf]*alpha + ssum;
        u16* pb = Pb[w] + (qf*16+lr)*72;
        #pragma unroll
        for (int st=0;st<4;++st){
          short4_t pk;
          pk.x=(short)f2b(S[qf][st][0]); pk.y=(short)f2b(S[qf][st][1]);
          pk.z=(short)f2b(S[qf][st][2]); pk.w=(short)f2b(S[qf][st][3]);
          *(short4_t*)(pb + st*16 + lq*4) = pk;
        }
        float af[4];
        #pragma unroll
        for (int r=0;r<4;++r) af[r] = __shfl(alpha, lq*4+r);
        #pragma unroll
        for (int dt=0;dt<4;++dt)
          #pragma unroll
          for (int r=0;r<4;++r) Oacc[qf][dt][r] *= af[r];
      }
      __asm__ volatile("s_waitcnt lgkmcnt(0)" ::: "memory");
      #pragma unroll
      for (int kk=0;kk<2;++kk){
        short8 pf0 = *(const short8*)(Pb[w] + (lr   )*72 + kk*32 + lq*8);
        short8 pf1 = *(const short8*)(Pb[w] + (16+lr)*72 + kk*32 + lq*8);
        #pragma unroll
        for (int dt=0;dt<4;++dt){
          short8 vf = *(const short8*)(Vt + (dt*16+lr)*72 + kk*32 + lq*8);
          Oacc[0][dt] = __builtin_amdgcn_mfma_f32_16x16x32_bf16(pf0, vf, Oacc[0][dt], 0,0,0);
          Oacc[1][dt] = __builtin_amdgcn_mfma_f32_16x16x32_bf16(pf1, vf, Oacc[1][dt], 0,0,0);
        }
      }
    }
  }
  float linv[2][4];
  #pragma unroll
  for (int qf=0;qf<2;++qf)
    #pragma unroll
    for (int r=0;r<4;++r) linv[qf][r] = 1.0f/__shfl(lrun[qf], lq*4+r);
  #pragma unroll
  for (int qf=0;qf<2;++qf)
    #pragma unroll
    for (int dt=0;dt<4;++dt)
      #pragma unroll
      for (int r=0;r<4;++r){
        int qg = qbase + w*32 + qf*16 + lq*4 + r;
        O[(size_t)(bb*T+qg)*E + h*64 + dt*16 + lr] = f2b(Oacc[qf][dt][r]*linv[qf][r]);
      }
}

// ---------------- host ----------------
extern "C" void kernel_launch(void* const* d_in, const int* in_sizes, int n_in,
                              void* d_out, int out_size, void* d_ws, size_t ws_size,
                              hipStream_t stream)
{
  (void)in_sizes; (void)n_in; (void)out_size; (void)ws_size;
  const float* x     = (const float*)d_in[0];
  const float* wq    = (const float*)d_in[1];
  const float* wk    = (const float*)d_in[2];
  const float* wv    = (const float*)d_in[3];
  const float* wproj = (const float*)d_in[4];
  const float* bproj = (const float*)d_in[5];
  const float* g1    = (const float*)d_in[6];
  const float* be1   = (const float*)d_in[7];
  const float* g2    = (const float*)d_in[8];
  const float* be2   = (const float*)d_in[9];
  const float* w1    = (const float*)d_in[10];
  const float* b1    = (const float*)d_in[11];
  const float* w2    = (const float*)d_in[12];
  const float* b2    = (const float*)d_in[13];
  float* out = (float*)d_out;

  char* ws = (char*)d_ws;
  size_t off = 0;
  auto alloc = [&](size_t bytes)->void*{ void* p = ws + off; off += (bytes + 255) & ~(size_t)255; return p; };
  u16* hnorm  = (u16*)alloc((size_t)4096*1024*2);
  u16* qkv    = (u16*)alloc((size_t)4096*3072*2);
  u16* attnO  = (u16*)alloc((size_t)4096*1024*2);
  u16* x2     = (u16*)alloc((size_t)4096*1024*2);
  u16* h2     = (u16*)alloc((size_t)4096*1024*2);
  u16* ffn1   = (u16*)alloc((size_t)4096*4096*2);
  u16* wqkvT  = (u16*)alloc((size_t)3072*1024*2);
  u16* wprojT = (u16*)alloc((size_t)1024*1024*2);
  u16* w1T    = (u16*)alloc((size_t)4096*1024*2);
  u16* w2T    = (u16*)alloc((size_t)1024*4096*2);

  qkv_repack  <<<dim3(16,48),256,0,stream>>>(wq,wk,wv,wqkvT);
  transpose_bt<<<dim3(16,16),256,0,stream>>>(wproj, wprojT, 1024, 1024);
  transpose_bt<<<dim3(64,16),256,0,stream>>>(w1,    w1T,    4096, 1024);
  transpose_bt<<<dim3(16,64),256,0,stream>>>(w2,    w2T,    1024, 4096);

  ln_kernel<1><<<4096,256,0,stream>>>(x, g1, be1, hnorm);
  gemm_bt<<<dim3(24,32),256,0,stream>>>(hnorm, wqkvT, qkv, nullptr, 4096,3072,1024, nullptr, nullptr, 0, 8);
  attn_kernel<<<dim3(16,32),256,0,stream>>>(qkv, attnO);
  gemm_bt<<<dim3(8,32),256,0,stream>>>(attnO, wprojT, x2, nullptr, 4096,1024,1024, bproj, hnorm, 0, 2);
  ln_kernel<0><<<4096,256,0,stream>>>(x2, g2, be2, h2);
  gemm_bt<<<dim3(32,32),256,0,stream>>>(h2, w1T, ffn1, nullptr, 4096,4096,1024, b1, nullptr, 1, 8);
  gemm_bt<<<dim3(8,32),256,0,stream>>>(ffn1, w2T, nullptr, out, 4096,1024,4096, b2, h2, 0, 2);
}

// Round 5
// 400.367 us; speedup vs baseline: 1.4832x; 1.0756x over previous
//
#include <hip/hip_runtime.h>
#include <stdint.h>

typedef unsigned short u16;
typedef __attribute__((ext_vector_type(8))) short short8;
typedef __attribute__((ext_vector_type(4))) short short4_t;
typedef __attribute__((ext_vector_type(4))) float f32x4;

__device__ __forceinline__ float b2f(u16 u){ union{unsigned i; float f;}v; v.i=((unsigned)u)<<16; return v.f; }
__device__ __forceinline__ u16 f2b(float f){ unsigned x=__float_as_uint(f); return (u16)((x + 0x7fffu + ((x>>16)&1u))>>16); }

#if __has_builtin(__builtin_amdgcn_exp2f)
#define EXP2F(x) __builtin_amdgcn_exp2f(x)
#else
#define EXP2F(x) exp2f(x)
#endif

__device__ __forceinline__ void async16(const void* g, void* l){
  __builtin_amdgcn_global_load_lds((const __attribute__((address_space(1))) void*)g,
                                   (__attribute__((address_space(3))) void*)l, 16, 0, 0);
}

// ---------------- LayerNorm (E=1024, one block per row) ----------------
template<int IN_F32>
__global__ __launch_bounds__(256) void ln_kernel(const void* __restrict__ xin,
    const float* __restrict__ g, const float* __restrict__ b, u16* __restrict__ y)
{
  const int E = 1024;
  int row = blockIdx.x, t = threadIdx.x;
  float f0,f1,f2,f3;
  if (IN_F32){
    const float* xr = (const float*)xin + (size_t)row*E;
    float4 xv = *(const float4*)(xr + t*4);
    f0=xv.x; f1=xv.y; f2=xv.z; f3=xv.w;
  } else {
    const u16* xr = (const u16*)xin + (size_t)row*E;
    ushort4 xv = *(const ushort4*)(xr + t*4);
    f0=b2f(xv.x); f1=b2f(xv.y); f2=b2f(xv.z); f3=b2f(xv.w);
  }
  float s1 = f0+f1+f2+f3;
  float s2 = f0*f0+f1*f1+f2*f2+f3*f3;
  #pragma unroll
  for (int off=32; off>=1; off>>=1){ s1 += __shfl_xor(s1,off); s2 += __shfl_xor(s2,off); }
  __shared__ float red[8];
  int w = t>>6;
  if ((t&63)==0){ red[w]=s1; red[4+w]=s2; }
  __syncthreads();
  float S1 = red[0]+red[1]+red[2]+red[3];
  float S2 = red[4]+red[5]+red[6]+red[7];
  float mean = S1*(1.0f/E);
  float var  = S2*(1.0f/E) - mean*mean;
  float inv  = rsqrtf(var + 1e-5f);
  float4 gv = *(const float4*)(g + t*4);
  float4 bv = *(const float4*)(b + t*4);
  ushort4 o;
  o.x = f2b((f0-mean)*inv*gv.x+bv.x);
  o.y = f2b((f1-mean)*inv*gv.y+bv.y);
  o.z = f2b((f2-mean)*inv*gv.z+bv.z);
  o.w = f2b((f3-mean)*inv*gv.w+bv.w);
  *(ushort4*)(y + (size_t)row*E + t*4) = o;
}

// ---------------- fp32->bf16 64x64-tiled transpose ----------------
__global__ __launch_bounds__(256) void transpose_bt(const float* __restrict__ src, u16* __restrict__ dst,
                                                    int ld_src, int ld_dst)
{
  __shared__ u16 tile[64*66];
  int c0 = blockIdx.x*64, r0 = blockIdx.y*64;
  int t = threadIdx.x;
  #pragma unroll
  for (int i=0;i<16;++i){
    int lin = i*256 + t;
    int rr = lin>>6, cc = lin&63;
    tile[cc*66+rr] = f2b(src[(size_t)(r0+rr)*ld_src + c0+cc]);
  }
  __syncthreads();
  #pragma unroll
  for (int i=0;i<16;++i){
    int lin = i*256 + t;
    int cc = lin>>6, rr = lin&63;
    dst[(size_t)(c0+cc)*ld_dst + r0+rr] = tile[cc*66+rr];
  }
}

// ---------------- QKV weight repack ----------------
__global__ __launch_bounds__(256) void qkv_repack(const float* __restrict__ wq, const float* __restrict__ wk,
                                                  const float* __restrict__ wv, u16* __restrict__ dst)
{
  __shared__ u16 tile[64*66];
  int e0 = blockIdx.x*64;
  int sel = blockIdx.y>>4, h = blockIdx.y&15;
  const float* src = (sel==0?wq:(sel==1?wk:wv)) + (size_t)h*1024*64;
  int t = threadIdx.x;
  #pragma unroll
  for (int i=0;i<16;++i){
    int lin=i*256+t; int rr=lin>>6, cc=lin&63;
    tile[cc*66+rr] = f2b(src[(size_t)(e0+rr)*64 + cc]);
  }
  __syncthreads();
  #pragma unroll
  for (int i=0;i<16;++i){
    int lin=i*256+t; int cc=lin>>6, rr=lin&63;
    dst[(size_t)(sel*1024 + h*64 + cc)*1024 + e0+rr] = tile[cc*66+rr];
  }
}

// ---------------- bf16 GEMM: C[M][N] = A[M][K] * Bt[N][K]^T ----------------
// Row-tile = MI*32 (MI=4 -> 128x128, MI=2 -> 64x128). BK=64, double-buffered
// LDS, global_load_lds width-16 prefetch, XOR-chunk swizzle so BK=64 rows
// (128B, all same bank phase) read conflict-free. XCD-compact block swizzle.
template<int MI>
__global__ __launch_bounds__(256, MI==2?3:2) void gemm_bt(const u16* __restrict__ A, const u16* __restrict__ Bt,
    u16* __restrict__ C, float* __restrict__ Cf, int M, int N, int K,
    const float* __restrict__ bias, const u16* __restrict__ residual, int do_relu, int gx)
{
  __shared__ __align__(16) u16 As[2][MI*32*64];
  __shared__ __align__(16) u16 Bs[2][128*64];
  int t = threadIdx.x;
  int bid = blockIdx.y * gridDim.x + blockIdx.x;
  int xcd = bid & 7, slot = bid >> 3;
  int gy = 8 / gx;
  int rx = gridDim.x / gx, ry = gridDim.y / gy;
  int col_b = (xcd % gx) * rx + (slot % rx);
  int row_b = (xcd / gx) * ry + (slot / rx);
  int row0 = row_b*(MI*32), col0 = col_b*128;
  int l = t&63, w = t>>6;
  int wm = (w>>1)*(MI*16), wn = (w&1)*64;
  int lr = l&15, lq = l>>4;
  (void)M;

  f32x4 acc[MI][4];
  #pragma unroll
  for (int i=0;i<MI;++i)
    #pragma unroll
    for (int j=0;j<4;++j) acc[i][j] = f32x4{0.f,0.f,0.f,0.f};

  // staging: thread t loads row (t>>3), k-chunk ((t&7)^((t>>3)&7)) of each
  // 32-row round; lands at LDS r*2048 + t*8 (contiguous, HW-forced layout).
  const u16* gA = A  + (size_t)(row0 + (t>>3))*K + (((t&7)^((t>>3)&7))<<3);
  const u16* gB = Bt + (size_t)(col0 + (t>>3))*K + (((t&7)^((t>>3)&7))<<3);
  const size_t rnd = (size_t)32*K;
  int nk = K>>6;

  #pragma unroll
  for (int r=0;r<MI;++r) async16(gA + r*rnd, As[0] + r*2048 + t*8);
  #pragma unroll
  for (int r=0;r<4;++r)  async16(gB + r*rnd, Bs[0] + r*2048 + t*8);

  int sw8 = (lr&7);
  for (int kt=0; kt<nk; ++kt){
    int cur = kt&1;
    __syncthreads();   // drains prefetch for 'cur'; guards reuse of 'cur^1'
    if (kt+1 < nk){
      int ko = (kt+1)<<6;
      #pragma unroll
      for (int r=0;r<MI;++r) async16(gA + r*rnd + ko, As[cur^1] + r*2048 + t*8);
      #pragma unroll
      for (int r=0;r<4;++r)  async16(gB + r*rnd + ko, Bs[cur^1] + r*2048 + t*8);
    }
    const u16* as = As[cur];
    const u16* bs = Bs[cur];
    #pragma unroll
    for (int kk=0;kk<2;++kk){
      int so = (((kk*4+lq)^sw8))<<3;
      short8 a[MI], b[4];
      #pragma unroll
      for (int i=0;i<MI;++i) a[i] = *(const short8*)(as + (wm+i*16+lr)*64 + so);
      #pragma unroll
      for (int j=0;j<4;++j)  b[j] = *(const short8*)(bs + (wn+j*16+lr)*64 + so);
      #pragma unroll
      for (int i=0;i<MI;++i)
        #pragma unroll
        for (int j=0;j<4;++j)
          acc[i][j] = __builtin_amdgcn_mfma_f32_16x16x32_bf16(a[i], b[j], acc[i][j], 0,0,0);
    }
  }

  #pragma unroll
  for (int i=0;i<MI;++i){
    #pragma unroll
    for (int j=0;j<4;++j){
      int col = col0 + wn + j*16 + lr;
      float bv = bias ? bias[col] : 0.0f;
      #pragma unroll
      for (int r=0;r<4;++r){
        int row = row0 + wm + i*16 + lq*4 + r;
        float v = acc[i][j][r] + bv;
        if (do_relu) v = fmaxf(v, 0.0f);
        if (residual) v += b2f(residual[(size_t)row*N + col]);
        if (Cf) Cf[(size_t)row*N + col] = v;
        else    C [(size_t)row*N + col] = f2b(v);
      }
    }
  }
}

// ---------------- causal flash attention v2 (XCD-swizzled) ----------------
__global__ __launch_bounds__(256) void attn_kernel(const u16* __restrict__ QKV, u16* __restrict__ O)
{
  const int T=2048, LD=3072, E=1024;
  int bid = blockIdx.y * gridDim.x + blockIdx.x;
  int xcd = bid & 7, slot = bid >> 3;
  int qt = 15 - (slot & 15);
  int bh = xcd*4 + (slot >> 4);
  int bb = bh>>4, h = bh&15;
  int qbase = qt*128;
  const u16* base = QKV + (size_t)bb*T*LD;
  const u16* Qp = base + h*64;
  const u16* Kp = base + 1024 + h*64;
  const u16* Vp = base + 2048 + h*64;
  int t = threadIdx.x, l = t&63, w = t>>6;
  int lr = l&15, lq = l>>4;

  __shared__ __align__(16) u16 Ks[64*64];
  __shared__ __align__(16) u16 Vt[64*72];
  __shared__ __align__(16) u16 Pb[4][32*72];

  const float QSC = 0.125f*1.44269504f;
  short8 aq[2][2];
  #pragma unroll
  for (int qf=0;qf<2;++qf)
    #pragma unroll
    for (int kk=0;kk<2;++kk){
      const u16* qp = Qp + (size_t)(qbase + w*32 + qf*16 + lr)*LD + kk*32 + lq*8;
      short8 raw = *(const short8*)qp;
      short8 sc;
      #pragma unroll
      for (int j=0;j<8;++j) sc[j] = (short)f2b(b2f((u16)raw[j])*QSC);
      aq[qf][kk]=sc;
    }

  float mrun[2] = {-3e38f,-3e38f}, lrun[2] = {0.f,0.f};
  f32x4 Oacc[2][4];
  #pragma unroll
  for (int qf=0;qf<2;++qf)
    #pragma unroll
    for (int dt=0;dt<4;++dt) Oacc[qf][dt] = f32x4{0.f,0.f,0.f,0.f};

  int kc = (l&7) ^ (l>>3);
  int s_a = 8*w + (l>>3);
  int sv = (l&31)*2;
  int vc0 = (t>>5)*8;
  int qw0 = qbase + w*32;

  int nIter = 2*qt + 2;
  for (int it=0; it<nIter; ++it){
    int s0 = it*64;
    __syncthreads();
    async16(Kp + (size_t)(s0+s_a)*LD    + kc*8, Ks + ((size_t)w*64       + l)*8);
    async16(Kp + (size_t)(s0+s_a+32)*LD + kc*8, Ks + ((size_t)(4+w)*64   + l)*8);
    {
      const u16* vp0 = Vp + (size_t)(s0+sv)*LD + vc0;
      ushort4 a0 = *(const ushort4*)vp0;
      ushort4 a1 = *(const ushort4*)(vp0+4);
      ushort4 b0 = *(const ushort4*)(vp0+LD);
      ushort4 b1 = *(const ushort4*)(vp0+LD+4);
      u16 av[8] = {a0.x,a0.y,a0.z,a0.w,a1.x,a1.y,a1.z,a1.w};
      u16 bv[8] = {b0.x,b0.y,b0.z,b0.w,b1.x,b1.y,b1.z,b1.w};
      #pragma unroll
      for (int kth=0;kth<8;++kth)
        *(uint*)(Vt + (size_t)(vc0+kth)*72 + sv) = (uint)av[kth] | ((uint)bv[kth]<<16);
    }
    __syncthreads();
    if (s0 <= qw0 + 31){
      bool need_mask = (s0 + 63 > qw0);
      f32x4 S[2][4];
      #pragma unroll
      for (int st=0; st<4; ++st){
        short8 kf0 = *(const short8*)(Ks + (st*16+lr)*64 + ((lq  )^(lr&7))*8);
        short8 kf1 = *(const short8*)(Ks + (st*16+lr)*64 + ((4+lq)^(lr&7))*8);
        #pragma unroll
        for (int qf=0;qf<2;++qf){
          f32x4 z = f32x4{0.f,0.f,0.f,0.f};
          z = __builtin_amdgcn_mfma_f32_16x16x32_bf16(kf0, aq[qf][0], z, 0,0,0);
          z = __builtin_amdgcn_mfma_f32_16x16x32_bf16(kf1, aq[qf][1], z, 0,0,0);
          S[qf][st] = z;
        }
      }
      if (need_mask){
        #pragma unroll
        for (int qf=0;qf<2;++qf){
          int qg = qw0 + qf*16 + lr;
          #pragma unroll
          for (int st=0;st<4;++st)
            #pragma unroll
            for (int r=0;r<4;++r){
              int sg = s0 + st*16 + lq*4 + r;
              if (sg > qg) S[qf][st][r] = -3e38f;
            }
        }
      }
      #pragma unroll
      for (int qf=0;qf<2;++qf){
        float m01 = fmaxf(fmaxf(S[qf][0][0],S[qf][0][1]),fmaxf(S[qf][0][2],S[qf][0][3]));
        float m11 = fmaxf(fmaxf(S[qf][1][0],S[qf][1][1]),fmaxf(S[qf][1][2],S[qf][1][3]));
        float m21 = fmaxf(fmaxf(S[qf][2][0],S[qf][2][1]),fmaxf(S[qf][2][2],S[qf][2][3]));
        float m31 = fmaxf(fmaxf(S[qf][3][0],S[qf][3][1]),fmaxf(S[qf][3][2],S[qf][3][3]));
        float m = fmaxf(fmaxf(m01,m11),fmaxf(m21,m31));
        m = fmaxf(m, __shfl_xor(m,16));
        m = fmaxf(m, __shfl_xor(m,32));
        float mnew = fmaxf(mrun[qf], m);
        float alpha = EXP2F(mrun[qf]-mnew);
        mrun[qf] = mnew;
        float ssum = 0.f;
        #pragma unroll
        for (int st=0;st<4;++st)
          #pragma unroll
          for (int r=0;r<4;++r){ float p = EXP2F(S[qf][st][r]-mnew); S[qf][st][r]=p; ssum+=p; }
        ssum += __shfl_xor(ssum,16);
        ssum += __shfl_xor(ssum,32);
        lrun[qf] = lrun[qf]*alpha + ssum;
        u16* pb = Pb[w] + (qf*16+lr)*72;
        #pragma unroll
        for (int st=0;st<4;++st){
          short4_t pk;
          pk.x=(short)f2b(S[qf][st][0]); pk.y=(short)f2b(S[qf][st][1]);
          pk.z=(short)f2b(S[qf][st][2]); pk.w=(short)f2b(S[qf][st][3]);
          *(short4_t*)(pb + st*16 + lq*4) = pk;
        }
        float af[4];
        #pragma unroll
        for (int r=0;r<4;++r) af[r] = __shfl(alpha, lq*4+r);
        #pragma unroll
        for (int dt=0;dt<4;++dt)
          #pragma unroll
          for (int r=0;r<4;++r) Oacc[qf][dt][r] *= af[r];
      }
      __asm__ volatile("s_waitcnt lgkmcnt(0)" ::: "memory");
      #pragma unroll
      for (int kk=0;kk<2;++kk){
        short8 pf0 = *(const short8*)(Pb[w] + (lr   )*72 + kk*32 + lq*8);
        short8 pf1 = *(const short8*)(Pb[w] + (16+lr)*72 + kk*32 + lq*8);
        #pragma unroll
        for (int dt=0;dt<4;++dt){
          short8 vf = *(const short8*)(Vt + (dt*16+lr)*72 + kk*32 + lq*8);
          Oacc[0][dt] = __builtin_amdgcn_mfma_f32_16x16x32_bf16(pf0, vf, Oacc[0][dt], 0,0,0);
          Oacc[1][dt] = __builtin_amdgcn_mfma_f32_16x16x32_bf16(pf1, vf, Oacc[1][dt], 0,0,0);
        }
      }
    }
  }
  float linv[2][4];
  #pragma unroll
  for (int qf=0;qf<2;++qf)
    #pragma unroll
    for (int r=0;r<4;++r) linv[qf][r] = 1.0f/__shfl(lrun[qf], lq*4+r);
  #pragma unroll
  for (int qf=0;qf<2;++qf)
    #pragma unroll
    for (int dt=0;dt<4;++dt)
      #pragma unroll
      for (int r=0;r<4;++r){
        int qg = qbase + w*32 + qf*16 + lq*4 + r;
        O[(size_t)(bb*T+qg)*E + h*64 + dt*16 + lr] = f2b(Oacc[qf][dt][r]*linv[qf][r]);
      }
}

// ---------------- host ----------------
extern "C" void kernel_launch(void* const* d_in, const int* in_sizes, int n_in,
                              void* d_out, int out_size, void* d_ws, size_t ws_size,
                              hipStream_t stream)
{
  (void)in_sizes; (void)n_in; (void)out_size; (void)ws_size;
  const float* x     = (const float*)d_in[0];
  const float* wq    = (const float*)d_in[1];
  const float* wk    = (const float*)d_in[2];
  const float* wv    = (const float*)d_in[3];
  const float* wproj = (const float*)d_in[4];
  const float* bproj = (const float*)d_in[5];
  const float* g1    = (const float*)d_in[6];
  const float* be1   = (const float*)d_in[7];
  const float* g2    = (const float*)d_in[8];
  const float* be2   = (const float*)d_in[9];
  const float* w1    = (const float*)d_in[10];
  const float* b1    = (const float*)d_in[11];
  const float* w2    = (const float*)d_in[12];
  const float* b2    = (const float*)d_in[13];
  float* out = (float*)d_out;

  char* ws = (char*)d_ws;
  size_t off = 0;
  auto alloc = [&](size_t bytes)->void*{ void* p = ws + off; off += (bytes + 255) & ~(size_t)255; return p; };
  u16* hnorm  = (u16*)alloc((size_t)4096*1024*2);
  u16* qkv    = (u16*)alloc((size_t)4096*3072*2);
  u16* attnO  = (u16*)alloc((size_t)4096*1024*2);
  u16* x2     = (u16*)alloc((size_t)4096*1024*2);
  u16* h2     = (u16*)alloc((size_t)4096*1024*2);
  u16* ffn1   = (u16*)alloc((size_t)4096*4096*2);
  u16* wqkvT  = (u16*)alloc((size_t)3072*1024*2);
  u16* wprojT = (u16*)alloc((size_t)1024*1024*2);
  u16* w1T    = (u16*)alloc((size_t)4096*1024*2);
  u16* w2T    = (u16*)alloc((size_t)1024*4096*2);

  qkv_repack  <<<dim3(16,48),256,0,stream>>>(wq,wk,wv,wqkvT);
  transpose_bt<<<dim3(16,16),256,0,stream>>>(wproj, wprojT, 1024, 1024);
  transpose_bt<<<dim3(64,16),256,0,stream>>>(w1,    w1T,    4096, 1024);
  transpose_bt<<<dim3(16,64),256,0,stream>>>(w2,    w2T,    1024, 4096);

  ln_kernel<1><<<4096,256,0,stream>>>(x, g1, be1, hnorm);
  gemm_bt<4><<<dim3(24,32),256,0,stream>>>(hnorm, wqkvT, qkv, nullptr, 4096,3072,1024, nullptr, nullptr, 0, 8);
  attn_kernel<<<dim3(16,32),256,0,stream>>>(qkv, attnO);
  gemm_bt<2><<<dim3(8,64),256,0,stream>>>(attnO, wprojT, x2, nullptr, 4096,1024,1024, bproj, hnorm, 0, 2);
  ln_kernel<0><<<4096,256,0,stream>>>(x2, g2, be2, h2);
  gemm_bt<4><<<dim3(32,32),256,0,stream>>>(h2, w1T, ffn1, nullptr, 4096,4096,1024, b1, nullptr, 1, 8);
  gemm_bt<2><<<dim3(8,64),256,0,stream>>>(ffn1, w2T, nullptr, out, 4096,1024,4096, b2, h2, 0, 2);
}

// Round 6
// 400.145 us; speedup vs baseline: 1.4840x; 1.0006x over previous
//
#include <hip/hip_runtime.h>
#include <stdint.h>

typedef unsigned short u16;
typedef __attribute__((ext_vector_type(8))) short short8;
typedef __attribute__((ext_vector_type(4))) short short4_t;
typedef __attribute__((ext_vector_type(4))) float f32x4;

__device__ __forceinline__ float b2f(u16 u){ union{unsigned i; float f;}v; v.i=((unsigned)u)<<16; return v.f; }
__device__ __forceinline__ u16 f2b(float f){ unsigned x=__float_as_uint(f); return (u16)((x + 0x7fffu + ((x>>16)&1u))>>16); }

#if __has_builtin(__builtin_amdgcn_exp2f)
#define EXP2F(x) __builtin_amdgcn_exp2f(x)
#else
#define EXP2F(x) exp2f(x)
#endif

__device__ __forceinline__ void async16(const void* g, void* l){
  __builtin_amdgcn_global_load_lds((const __attribute__((address_space(1))) void*)g,
                                   (__attribute__((address_space(3))) void*)l, 16, 0, 0);
}

// ---------------- LayerNorm (E=1024, one block per row) ----------------
template<int IN_F32>
__global__ __launch_bounds__(256) void ln_kernel(const void* __restrict__ xin,
    const float* __restrict__ g, const float* __restrict__ b, u16* __restrict__ y)
{
  const int E = 1024;
  int row = blockIdx.x, t = threadIdx.x;
  float f0,f1,f2,f3;
  if (IN_F32){
    const float* xr = (const float*)xin + (size_t)row*E;
    float4 xv = *(const float4*)(xr + t*4);
    f0=xv.x; f1=xv.y; f2=xv.z; f3=xv.w;
  } else {
    const u16* xr = (const u16*)xin + (size_t)row*E;
    ushort4 xv = *(const ushort4*)(xr + t*4);
    f0=b2f(xv.x); f1=b2f(xv.y); f2=b2f(xv.z); f3=b2f(xv.w);
  }
  float s1 = f0+f1+f2+f3;
  float s2 = f0*f0+f1*f1+f2*f2+f3*f3;
  #pragma unroll
  for (int off=32; off>=1; off>>=1){ s1 += __shfl_xor(s1,off); s2 += __shfl_xor(s2,off); }
  __shared__ float red[8];
  int w = t>>6;
  if ((t&63)==0){ red[w]=s1; red[4+w]=s2; }
  __syncthreads();
  float S1 = red[0]+red[1]+red[2]+red[3];
  float S2 = red[4]+red[5]+red[6]+red[7];
  float mean = S1*(1.0f/E);
  float var  = S2*(1.0f/E) - mean*mean;
  float inv  = rsqrtf(var + 1e-5f);
  float4 gv = *(const float4*)(g + t*4);
  float4 bv = *(const float4*)(b + t*4);
  ushort4 o;
  o.x = f2b((f0-mean)*inv*gv.x+bv.x);
  o.y = f2b((f1-mean)*inv*gv.y+bv.y);
  o.z = f2b((f2-mean)*inv*gv.z+bv.z);
  o.w = f2b((f3-mean)*inv*gv.w+bv.w);
  *(ushort4*)(y + (size_t)row*E + t*4) = o;
}

// ---------------- fp32->bf16 64x64-tiled transpose ----------------
__global__ __launch_bounds__(256) void transpose_bt(const float* __restrict__ src, u16* __restrict__ dst,
                                                    int ld_src, int ld_dst)
{
  __shared__ u16 tile[64*66];
  int c0 = blockIdx.x*64, r0 = blockIdx.y*64;
  int t = threadIdx.x;
  #pragma unroll
  for (int i=0;i<16;++i){
    int lin = i*256 + t;
    int rr = lin>>6, cc = lin&63;
    tile[cc*66+rr] = f2b(src[(size_t)(r0+rr)*ld_src + c0+cc]);
  }
  __syncthreads();
  #pragma unroll
  for (int i=0;i<16;++i){
    int lin = i*256 + t;
    int cc = lin>>6, rr = lin&63;
    dst[(size_t)(c0+cc)*ld_dst + r0+rr] = tile[cc*66+rr];
  }
}

// ---------------- QKV weight repack ----------------
__global__ __launch_bounds__(256) void qkv_repack(const float* __restrict__ wq, const float* __restrict__ wk,
                                                  const float* __restrict__ wv, u16* __restrict__ dst)
{
  __shared__ u16 tile[64*66];
  int e0 = blockIdx.x*64;
  int sel = blockIdx.y>>4, h = blockIdx.y&15;
  const float* src = (sel==0?wq:(sel==1?wk:wv)) + (size_t)h*1024*64;
  int t = threadIdx.x;
  #pragma unroll
  for (int i=0;i<16;++i){
    int lin=i*256+t; int rr=lin>>6, cc=lin&63;
    tile[cc*66+rr] = f2b(src[(size_t)(e0+rr)*64 + cc]);
  }
  __syncthreads();
  #pragma unroll
  for (int i=0;i<16;++i){
    int lin=i*256+t; int cc=lin>>6, rr=lin&63;
    dst[(size_t)(sel*1024 + h*64 + cc)*1024 + e0+rr] = tile[cc*66+rr];
  }
}

// ---------------- V transpose: qkv V-slice -> VT[bh][64][2048] ----------------
// grid = (32 s-tiles, 32 bh). Coalesced in, coalesced out via 64x66 LDS tile.
__global__ __launch_bounds__(256) void vtrans(const u16* __restrict__ qkv, u16* __restrict__ VT)
{
  __shared__ u16 tile[64*66];
  int bh = blockIdx.y, bb = bh>>4, h = bh&15;
  int s0 = blockIdx.x*64;
  const u16* src = qkv + ((size_t)(bb*2048) + s0)*3072 + 2048 + h*64;
  int t = threadIdx.x;
  int sr = t>>3, c0 = (t&7)*8;
  #pragma unroll
  for (int half=0; half<2; ++half){
    const u16* p = src + (size_t)(sr+half*32)*3072 + c0;
    ushort4 v0 = *(const ushort4*)p;
    ushort4 v1 = *(const ushort4*)(p+4);
    uint* d = (uint*)(tile + (sr+half*32)*66 + c0);
    d[0] = (uint)v0.x | ((uint)v0.y<<16);
    d[1] = (uint)v0.z | ((uint)v0.w<<16);
    d[2] = (uint)v1.x | ((uint)v1.y<<16);
    d[3] = (uint)v1.z | ((uint)v1.w<<16);
  }
  __syncthreads();
  u16* out = VT + (size_t)bh*64*2048 + s0;
  int dw = t>>3, sc = (t&7)*8;
  #pragma unroll
  for (int half=0; half<2; ++half){
    int d = dw + half*32;
    short8 pk;
    #pragma unroll
    for (int j=0;j<8;++j) pk[j] = (short)tile[(sc+j)*66 + d];
    *(short8*)(out + (size_t)d*2048 + sc) = pk;
  }
}

// ---------------- bf16 GEMM: C[M][N] = A[M][K] * Bt[N][K]^T ----------------
template<int MI>
__global__ __launch_bounds__(256, 3) void gemm_bt(const u16* __restrict__ A, const u16* __restrict__ Bt,
    u16* __restrict__ C, float* __restrict__ Cf, int M, int N, int K,
    const float* __restrict__ bias, const u16* __restrict__ residual, int do_relu, int gx)
{
  __shared__ __align__(16) u16 As[2][MI*32*64];
  __shared__ __align__(16) u16 Bs[2][128*64];
  int t = threadIdx.x;
  int bid = blockIdx.y * gridDim.x + blockIdx.x;
  int xcd = bid & 7, slot = bid >> 3;
  int gy = 8 / gx;
  int rx = gridDim.x / gx, ry = gridDim.y / gy;
  int col_b = (xcd % gx) * rx + (slot % rx);
  int row_b = (xcd / gx) * ry + (slot / rx);
  int row0 = row_b*(MI*32), col0 = col_b*128;
  int l = t&63, w = t>>6;
  int wm = (w>>1)*(MI*16), wn = (w&1)*64;
  int lr = l&15, lq = l>>4;
  (void)M;

  f32x4 acc[MI][4];
  #pragma unroll
  for (int i=0;i<MI;++i)
    #pragma unroll
    for (int j=0;j<4;++j) acc[i][j] = f32x4{0.f,0.f,0.f,0.f};

  const u16* gA = A  + (size_t)(row0 + (t>>3))*K + (((t&7)^((t>>3)&7))<<3);
  const u16* gB = Bt + (size_t)(col0 + (t>>3))*K + (((t&7)^((t>>3)&7))<<3);
  const size_t rnd = (size_t)32*K;
  int nk = K>>6;

  #pragma unroll
  for (int r=0;r<MI;++r) async16(gA + r*rnd, As[0] + r*2048 + t*8);
  #pragma unroll
  for (int r=0;r<4;++r)  async16(gB + r*rnd, Bs[0] + r*2048 + t*8);

  int sw8 = (lr&7);
  for (int kt=0; kt<nk; ++kt){
    int cur = kt&1;
    __syncthreads();
    if (kt+1 < nk){
      int ko = (kt+1)<<6;
      #pragma unroll
      for (int r=0;r<MI;++r) async16(gA + r*rnd + ko, As[cur^1] + r*2048 + t*8);
      #pragma unroll
      for (int r=0;r<4;++r)  async16(gB + r*rnd + ko, Bs[cur^1] + r*2048 + t*8);
    }
    const u16* as = As[cur];
    const u16* bs = Bs[cur];
    #pragma unroll
    for (int kk=0;kk<2;++kk){
      int so = (((kk*4+lq)^sw8))<<3;
      short8 a[MI], b[4];
      #pragma unroll
      for (int i=0;i<MI;++i) a[i] = *(const short8*)(as + (wm+i*16+lr)*64 + so);
      #pragma unroll
      for (int j=0;j<4;++j)  b[j] = *(const short8*)(bs + (wn+j*16+lr)*64 + so);
      #pragma unroll
      for (int i=0;i<MI;++i)
        #pragma unroll
        for (int j=0;j<4;++j)
          acc[i][j] = __builtin_amdgcn_mfma_f32_16x16x32_bf16(a[i], b[j], acc[i][j], 0,0,0);
    }
  }

  #pragma unroll
  for (int i=0;i<MI;++i){
    #pragma unroll
    for (int j=0;j<4;++j){
      int col = col0 + wn + j*16 + lr;
      float bv = bias ? bias[col] : 0.0f;
      #pragma unroll
      for (int r=0;r<4;++r){
        int row = row0 + wm + i*16 + lq*4 + r;
        float v = acc[i][j][r] + bv;
        if (do_relu) v = fmaxf(v, 0.0f);
        if (residual) v += b2f(residual[(size_t)row*N + col]);
        if (Cf) Cf[(size_t)row*N + col] = v;
        else    C [(size_t)row*N + col] = f2b(v);
      }
    }
  }
}

// ---------------- causal flash attention v3 ----------------
// K and V^T both staged via global_load_lds (XOR-chunk swizzle), double-
// buffered s-tiles of 64. Q-tile 128 (wave=32 q rows). S^T = op(K,Q).
__global__ __launch_bounds__(256) void attn_kernel(const u16* __restrict__ QKV,
    const u16* __restrict__ VT, u16* __restrict__ O)
{
  const int T=2048, LD=3072, E=1024;
  int bid = blockIdx.y * gridDim.x + blockIdx.x;
  int xcd = bid & 7, slot = bid >> 3;
  int qt = 15 - (slot & 15);
  int bh = xcd*4 + (slot >> 4);
  int bb = bh>>4, h = bh&15;
  int qbase = qt*128;
  const u16* base = QKV + (size_t)bb*T*LD;
  const u16* Qp = base + h*64;
  const u16* Kp = base + 1024 + h*64;
  const u16* Vtp = VT + (size_t)bh*64*2048;
  int t = threadIdx.x, l = t&63, w = t>>6;
  int lr = l&15, lq = l>>4;

  __shared__ __align__(16) u16 Ks[2][64*64];   // [s][hd], chunk c at c^(s&7)
  __shared__ __align__(16) u16 Vs[2][64*64];   // [d][s],  chunk c at c^(d&7)
  __shared__ __align__(16) u16 Pb[4][32*72];   // per-wave P [q][s], ld 72

  const float QSC = 0.125f*1.44269504f;
  short8 aq[2][2];
  #pragma unroll
  for (int qf=0;qf<2;++qf)
    #pragma unroll
    for (int kk=0;kk<2;++kk){
      const u16* qp = Qp + (size_t)(qbase + w*32 + qf*16 + lr)*LD + kk*32 + lq*8;
      short8 raw = *(const short8*)qp;
      short8 sc;
      #pragma unroll
      for (int j=0;j<8;++j) sc[j] = (short)f2b(b2f((u16)raw[j])*QSC);
      aq[qf][kk]=sc;
    }

  float mrun[2] = {-3e38f,-3e38f}, lrun[2] = {0.f,0.f};
  f32x4 Oacc[2][4];
  #pragma unroll
  for (int qf=0;qf<2;++qf)
    #pragma unroll
    for (int dt=0;dt<4;++dt) Oacc[qf][dt] = f32x4{0.f,0.f,0.f,0.f};

  int kc = (l&7) ^ (l>>3);
  int ra = 8*w + (l>>3);       // staged row (K: s-row; V: d-row), +32 second
  int qw0 = qbase + w*32;
  int nIter = 2*qt + 2;

  // prologue: stage tile 0 into buffer 0
  async16(Kp + (size_t)ra*LD      + kc*8, Ks[0] + ((size_t)w*64     + l)*8);
  async16(Kp + (size_t)(ra+32)*LD + kc*8, Ks[0] + ((size_t)(4+w)*64 + l)*8);
  async16(Vtp + (size_t)ra*2048      + kc*8, Vs[0] + ((size_t)w*64     + l)*8);
  async16(Vtp + (size_t)(ra+32)*2048 + kc*8, Vs[0] + ((size_t)(4+w)*64 + l)*8);

  for (int it=0; it<nIter; ++it){
    int s0 = it*64, cur = it&1;
    __syncthreads();   // drains stage of 'cur'; guards reuse of 'cur^1'
    if (it+1 < nIter){
      int sn = (it+1)*64;
      u16* kd = Ks[cur^1]; u16* vd = Vs[cur^1];
      async16(Kp + (size_t)(sn+ra)*LD      + kc*8, kd + ((size_t)w*64     + l)*8);
      async16(Kp + (size_t)(sn+ra+32)*LD   + kc*8, kd + ((size_t)(4+w)*64 + l)*8);
      async16(Vtp + (size_t)(ra)*2048    + sn + kc*8, vd + ((size_t)w*64     + l)*8);
      async16(Vtp + (size_t)(ra+32)*2048 + sn + kc*8, vd + ((size_t)(4+w)*64 + l)*8);
    }
    if (s0 <= qw0 + 31){
      const u16* ks = Ks[cur];
      const u16* vs = Vs[cur];
      bool need_mask = (s0 + 63 > qw0);
      f32x4 S[2][4];
      #pragma unroll
      for (int st=0; st<4; ++st){
        short8 kf0 = *(const short8*)(ks + (st*16+lr)*64 + ((lq  )^(lr&7))*8);
        short8 kf1 = *(const short8*)(ks + (st*16+lr)*64 + ((4+lq)^(lr&7))*8);
        #pragma unroll
        for (int qf=0;qf<2;++qf){
          f32x4 z = f32x4{0.f,0.f,0.f,0.f};
          z = __builtin_amdgcn_mfma_f32_16x16x32_bf16(kf0, aq[qf][0], z, 0,0,0);
          z = __builtin_amdgcn_mfma_f32_16x16x32_bf16(kf1, aq[qf][1], z, 0,0,0);
          S[qf][st] = z;
        }
      }
      if (need_mask){
        #pragma unroll
        for (int qf=0;qf<2;++qf){
          int qg = qw0 + qf*16 + lr;
          #pragma unroll
          for (int st=0;st<4;++st)
            #pragma unroll
            for (int r=0;r<4;++r){
              int sg = s0 + st*16 + lq*4 + r;
              if (sg > qg) S[qf][st][r] = -3e38f;
            }
        }
      }
      #pragma unroll
      for (int qf=0;qf<2;++qf){
        float m01 = fmaxf(fmaxf(S[qf][0][0],S[qf][0][1]),fmaxf(S[qf][0][2],S[qf][0][3]));
        float m11 = fmaxf(fmaxf(S[qf][1][0],S[qf][1][1]),fmaxf(S[qf][1][2],S[qf][1][3]));
        float m21 = fmaxf(fmaxf(S[qf][2][0],S[qf][2][1]),fmaxf(S[qf][2][2],S[qf][2][3]));
        float m31 = fmaxf(fmaxf(S[qf][3][0],S[qf][3][1]),fmaxf(S[qf][3][2],S[qf][3][3]));
        float m = fmaxf(fmaxf(m01,m11),fmaxf(m21,m31));
        m = fmaxf(m, __shfl_xor(m,16));
        m = fmaxf(m, __shfl_xor(m,32));
        float mnew = fmaxf(mrun[qf], m);
        float alpha = EXP2F(mrun[qf]-mnew);
        mrun[qf] = mnew;
        float ssum = 0.f;
        #pragma unroll
        for (int st=0;st<4;++st)
          #pragma unroll
          for (int r=0;r<4;++r){ float p = EXP2F(S[qf][st][r]-mnew); S[qf][st][r]=p; ssum+=p; }
        ssum += __shfl_xor(ssum,16);
        ssum += __shfl_xor(ssum,32);
        lrun[qf] = lrun[qf]*alpha + ssum;
        u16* pb = Pb[w] + (qf*16+lr)*72;
        #pragma unroll
        for (int st=0;st<4;++st){
          short4_t pk;
          pk.x=(short)f2b(S[qf][st][0]); pk.y=(short)f2b(S[qf][st][1]);
          pk.z=(short)f2b(S[qf][st][2]); pk.w=(short)f2b(S[qf][st][3]);
          *(short4_t*)(pb + st*16 + lq*4) = pk;
        }
        float af[4];
        #pragma unroll
        for (int r=0;r<4;++r) af[r] = __shfl(alpha, lq*4+r);
        #pragma unroll
        for (int dt=0;dt<4;++dt)
          #pragma unroll
          for (int r=0;r<4;++r) Oacc[qf][dt][r] *= af[r];
      }
      __asm__ volatile("s_waitcnt lgkmcnt(0)" ::: "memory");
      #pragma unroll
      for (int kk=0;kk<2;++kk){
        short8 pf0 = *(const short8*)(Pb[w] + (lr   )*72 + kk*32 + lq*8);
        short8 pf1 = *(const short8*)(Pb[w] + (16+lr)*72 + kk*32 + lq*8);
        #pragma unroll
        for (int dt=0;dt<4;++dt){
          short8 vf = *(const short8*)(vs + (dt*16+lr)*64 + (((kk*4+lq)^(lr&7)))*8);
          Oacc[0][dt] = __builtin_amdgcn_mfma_f32_16x16x32_bf16(pf0, vf, Oacc[0][dt], 0,0,0);
          Oacc[1][dt] = __builtin_amdgcn_mfma_f32_16x16x32_bf16(pf1, vf, Oacc[1][dt], 0,0,0);
        }
      }
    }
  }
  float linv[2][4];
  #pragma unroll
  for (int qf=0;qf<2;++qf)
    #pragma unroll
    for (int r=0;r<4;++r) linv[qf][r] = 1.0f/__shfl(lrun[qf], lq*4+r);
  #pragma unroll
  for (int qf=0;qf<2;++qf)
    #pragma unroll
    for (int dt=0;dt<4;++dt)
      #pragma unroll
      for (int r=0;r<4;++r){
        int qg = qbase + w*32 + qf*16 + lq*4 + r;
        O[(size_t)(bb*T+qg)*E + h*64 + dt*16 + lr] = f2b(Oacc[qf][dt][r]*linv[qf][r]);
      }
}

// ---------------- host ----------------
extern "C" void kernel_launch(void* const* d_in, const int* in_sizes, int n_in,
                              void* d_out, int out_size, void* d_ws, size_t ws_size,
                              hipStream_t stream)
{
  (void)in_sizes; (void)n_in; (void)out_size; (void)ws_size;
  const float* x     = (const float*)d_in[0];
  const float* wq    = (const float*)d_in[1];
  const float* wk    = (const float*)d_in[2];
  const float* wv    = (const float*)d_in[3];
  const float* wproj = (const float*)d_in[4];
  const float* bproj = (const float*)d_in[5];
  const float* g1    = (const float*)d_in[6];
  const float* be1   = (const float*)d_in[7];
  const float* g2    = (const float*)d_in[8];
  const float* be2   = (const float*)d_in[9];
  const float* w1    = (const float*)d_in[10];
  const float* b1    = (const float*)d_in[11];
  const float* w2    = (const float*)d_in[12];
  const float* b2    = (const float*)d_in[13];
  float* out = (float*)d_out;

  char* ws = (char*)d_ws;
  size_t off = 0;
  auto alloc = [&](size_t bytes)->void*{ void* p = ws + off; off += (bytes + 255) & ~(size_t)255; return p; };
  u16* hnorm  = (u16*)alloc((size_t)4096*1024*2);
  u16* qkv    = (u16*)alloc((size_t)4096*3072*2);
  u16* VT     = (u16*)alloc((size_t)32*64*2048*2);
  u16* attnO  = (u16*)alloc((size_t)4096*1024*2);
  u16* x2     = (u16*)alloc((size_t)4096*1024*2);
  u16* h2     = (u16*)alloc((size_t)4096*1024*2);
  u16* ffn1   = (u16*)alloc((size_t)4096*4096*2);
  u16* wqkvT  = (u16*)alloc((size_t)3072*1024*2);
  u16* wprojT = (u16*)alloc((size_t)1024*1024*2);
  u16* w1T    = (u16*)alloc((size_t)4096*1024*2);
  u16* w2T    = (u16*)alloc((size_t)1024*4096*2);

  qkv_repack  <<<dim3(16,48),256,0,stream>>>(wq,wk,wv,wqkvT);
  transpose_bt<<<dim3(16,16),256,0,stream>>>(wproj, wprojT, 1024, 1024);
  transpose_bt<<<dim3(64,16),256,0,stream>>>(w1,    w1T,    4096, 1024);
  transpose_bt<<<dim3(16,64),256,0,stream>>>(w2,    w2T,    1024, 4096);

  ln_kernel<1><<<4096,256,0,stream>>>(x, g1, be1, hnorm);
  gemm_bt<4><<<dim3(24,32),256,0,stream>>>(hnorm, wqkvT, qkv, nullptr, 4096,3072,1024, nullptr, nullptr, 0, 8);
  vtrans<<<dim3(32,32),256,0,stream>>>(qkv, VT);
  attn_kernel<<<dim3(16,32),256,0,stream>>>(qkv, VT, attnO);
  gemm_bt<2><<<dim3(8,64),256,0,stream>>>(attnO, wprojT, x2, nullptr, 4096,1024,1024, bproj, hnorm, 0, 2);
  ln_kernel<0><<<4096,256,0,stream>>>(x2, g2, be2, h2);
  gemm_bt<4><<<dim3(32,32),256,0,stream>>>(h2, w1T, ffn1, nullptr, 4096,4096,1024, b1, nullptr, 1, 8);
  gemm_bt<2><<<dim3(8,64),256,0,stream>>>(ffn1, w2T, nullptr, out, 4096,1024,4096, b2, h2, 0, 2);
}

// Round 7
// 367.650 us; speedup vs baseline: 1.6152x; 1.0884x over previous
//
#include <hip/hip_runtime.h>
#include <stdint.h>

typedef unsigned short u16;
typedef __attribute__((ext_vector_type(8))) short short8;
typedef __attribute__((ext_vector_type(4))) short short4_t;
typedef __attribute__((ext_vector_type(4))) float f32x4;

__device__ __forceinline__ float b2f(u16 u){ union{unsigned i; float f;}v; v.i=((unsigned)u)<<16; return v.f; }
__device__ __forceinline__ u16 f2b(float f){ unsigned x=__float_as_uint(f); return (u16)((x + 0x7fffu + ((x>>16)&1u))>>16); }

#if __has_builtin(__builtin_amdgcn_exp2f)
#define EXP2F(x) __builtin_amdgcn_exp2f(x)
#else
#define EXP2F(x) exp2f(x)
#endif

#if __has_builtin(__builtin_amdgcn_mfma_f32_16x16x16_bf16)
#define MFMA16(a,b,c) __builtin_amdgcn_mfma_f32_16x16x16_bf16(a,b,c,0,0,0)
#elif __has_builtin(__builtin_amdgcn_mfma_f32_16x16x16bf16_1k)
#define MFMA16(a,b,c) __builtin_amdgcn_mfma_f32_16x16x16bf16_1k(a,b,c,0,0,0)
#else
static __device__ __forceinline__ f32x4 mfma16_asm(short4_t a, short4_t b, f32x4 c){
  __asm__("v_mfma_f32_16x16x16_bf16 %0, %1, %2, %3" : "=v"(c) : "v"(a), "v"(b), "0"(c));
  return c;
}
#define MFMA16(a,b,c) mfma16_asm(a,b,c)
#endif

__device__ __forceinline__ void async16(const void* g, void* l){
  __builtin_amdgcn_global_load_lds((const __attribute__((address_space(1))) void*)g,
                                   (__attribute__((address_space(3))) void*)l, 16, 0, 0);
}

// pack 4 fp32 (in [0,1]) -> 4 bf16 (round-half-up) as K=16 A-fragment regs
__device__ __forceinline__ short4_t pack4(f32x4 s){
  unsigned u0 = (__float_as_uint(s[0]) + 0x8000u) >> 16;
  unsigned u1 = (__float_as_uint(s[1]) + 0x8000u) & 0xffff0000u;
  unsigned u2 = (__float_as_uint(s[2]) + 0x8000u) >> 16;
  unsigned u3 = (__float_as_uint(s[3]) + 0x8000u) & 0xffff0000u;
  union { unsigned v[2]; short4_t s4; } r;
  r.v[0] = u0 | u1; r.v[1] = u2 | u3;
  return r.s4;
}

// ---------------- LayerNorm (E=1024, one block per row) ----------------
template<int IN_F32>
__global__ __launch_bounds__(256) void ln_kernel(const void* __restrict__ xin,
    const float* __restrict__ g, const float* __restrict__ b, u16* __restrict__ y)
{
  const int E = 1024;
  int row = blockIdx.x, t = threadIdx.x;
  float f0,f1,f2,f3;
  if (IN_F32){
    const float* xr = (const float*)xin + (size_t)row*E;
    float4 xv = *(const float4*)(xr + t*4);
    f0=xv.x; f1=xv.y; f2=xv.z; f3=xv.w;
  } else {
    const u16* xr = (const u16*)xin + (size_t)row*E;
    ushort4 xv = *(const ushort4*)(xr + t*4);
    f0=b2f(xv.x); f1=b2f(xv.y); f2=b2f(xv.z); f3=b2f(xv.w);
  }
  float s1 = f0+f1+f2+f3;
  float s2 = f0*f0+f1*f1+f2*f2+f3*f3;
  #pragma unroll
  for (int off=32; off>=1; off>>=1){ s1 += __shfl_xor(s1,off); s2 += __shfl_xor(s2,off); }
  __shared__ float red[8];
  int w = t>>6;
  if ((t&63)==0){ red[w]=s1; red[4+w]=s2; }
  __syncthreads();
  float S1 = red[0]+red[1]+red[2]+red[3];
  float S2 = red[4]+red[5]+red[6]+red[7];
  float mean = S1*(1.0f/E);
  float var  = S2*(1.0f/E) - mean*mean;
  float inv  = rsqrtf(var + 1e-5f);
  float4 gv = *(const float4*)(g + t*4);
  float4 bv = *(const float4*)(b + t*4);
  ushort4 o;
  o.x = f2b((f0-mean)*inv*gv.x+bv.x);
  o.y = f2b((f1-mean)*inv*gv.y+bv.y);
  o.z = f2b((f2-mean)*inv*gv.z+bv.z);
  o.w = f2b((f3-mean)*inv*gv.w+bv.w);
  *(ushort4*)(y + (size_t)row*E + t*4) = o;
}

// ---------------- fp32->bf16 64x64-tiled transpose ----------------
__global__ __launch_bounds__(256) void transpose_bt(const float* __restrict__ src, u16* __restrict__ dst,
                                                    int ld_src, int ld_dst)
{
  __shared__ u16 tile[64*66];
  int c0 = blockIdx.x*64, r0 = blockIdx.y*64;
  int t = threadIdx.x;
  #pragma unroll
  for (int i=0;i<16;++i){
    int lin = i*256 + t;
    int rr = lin>>6, cc = lin&63;
    tile[cc*66+rr] = f2b(src[(size_t)(r0+rr)*ld_src + c0+cc]);
  }
  __syncthreads();
  #pragma unroll
  for (int i=0;i<16;++i){
    int lin = i*256 + t;
    int cc = lin>>6, rr = lin&63;
    dst[(size_t)(c0+cc)*ld_dst + r0+rr] = tile[cc*66+rr];
  }
}

// ---------------- QKV weight repack ----------------
__global__ __launch_bounds__(256) void qkv_repack(const float* __restrict__ wq, const float* __restrict__ wk,
                                                  const float* __restrict__ wv, u16* __restrict__ dst)
{
  __shared__ u16 tile[64*66];
  int e0 = blockIdx.x*64;
  int sel = blockIdx.y>>4, h = blockIdx.y&15;
  const float* src = (sel==0?wq:(sel==1?wk:wv)) + (size_t)h*1024*64;
  int t = threadIdx.x;
  #pragma unroll
  for (int i=0;i<16;++i){
    int lin=i*256+t; int rr=lin>>6, cc=lin&63;
    tile[cc*66+rr] = f2b(src[(size_t)(e0+rr)*64 + cc]);
  }
  __syncthreads();
  #pragma unroll
  for (int i=0;i<16;++i){
    int lin=i*256+t; int cc=lin>>6, rr=lin&63;
    dst[(size_t)(sel*1024 + h*64 + cc)*1024 + e0+rr] = tile[cc*66+rr];
  }
}

// ---------------- V transpose: qkv V-slice -> VT[bh][64][2048] ----------------
__global__ __launch_bounds__(256) void vtrans(const u16* __restrict__ qkv, u16* __restrict__ VT)
{
  __shared__ u16 tile[64*66];
  int bh = blockIdx.y, bb = bh>>4, h = bh&15;
  int s0 = blockIdx.x*64;
  const u16* src = qkv + ((size_t)(bb*2048) + s0)*3072 + 2048 + h*64;
  int t = threadIdx.x;
  int sr = t>>3, c0 = (t&7)*8;
  #pragma unroll
  for (int half=0; half<2; ++half){
    const u16* p = src + (size_t)(sr+half*32)*3072 + c0;
    ushort4 v0 = *(const ushort4*)p;
    ushort4 v1 = *(const ushort4*)(p+4);
    uint* d = (uint*)(tile + (sr+half*32)*66 + c0);
    d[0] = (uint)v0.x | ((uint)v0.y<<16);
    d[1] = (uint)v0.z | ((uint)v0.w<<16);
    d[2] = (uint)v1.x | ((uint)v1.y<<16);
    d[3] = (uint)v1.z | ((uint)v1.w<<16);
  }
  __syncthreads();
  u16* out = VT + (size_t)bh*64*2048 + s0;
  int dw = t>>3, sc = (t&7)*8;
  #pragma unroll
  for (int half=0; half<2; ++half){
    int d = dw + half*32;
    short8 pk;
    #pragma unroll
    for (int j=0;j<8;++j) pk[j] = (short)tile[(sc+j)*66 + d];
    *(short8*)(out + (size_t)d*2048 + sc) = pk;
  }
}

// ---------------- bf16 GEMM: C[M][N] = A[M][K] * Bt[N][K]^T ----------------
template<int MI>
__global__ __launch_bounds__(256, 3) void gemm_bt(const u16* __restrict__ A, const u16* __restrict__ Bt,
    u16* __restrict__ C, float* __restrict__ Cf, int M, int N, int K,
    const float* __restrict__ bias, const u16* __restrict__ residual, int do_relu, int gx)
{
  __shared__ __align__(16) u16 As[2][MI*32*64];
  __shared__ __align__(16) u16 Bs[2][128*64];
  int t = threadIdx.x;
  int bid = blockIdx.y * gridDim.x + blockIdx.x;
  int xcd = bid & 7, slot = bid >> 3;
  int gy = 8 / gx;
  int rx = gridDim.x / gx, ry = gridDim.y / gy;
  int col_b = (xcd % gx) * rx + (slot % rx);
  int row_b = (xcd / gx) * ry + (slot / rx);
  int row0 = row_b*(MI*32), col0 = col_b*128;
  int l = t&63, w = t>>6;
  int wm = (w>>1)*(MI*16), wn = (w&1)*64;
  int lr = l&15, lq = l>>4;
  (void)M;

  f32x4 acc[MI][4];
  #pragma unroll
  for (int i=0;i<MI;++i)
    #pragma unroll
    for (int j=0;j<4;++j) acc[i][j] = f32x4{0.f,0.f,0.f,0.f};

  const u16* gA = A  + (size_t)(row0 + (t>>3))*K + (((t&7)^((t>>3)&7))<<3);
  const u16* gB = Bt + (size_t)(col0 + (t>>3))*K + (((t&7)^((t>>3)&7))<<3);
  const size_t rnd = (size_t)32*K;
  int nk = K>>6;

  #pragma unroll
  for (int r=0;r<MI;++r) async16(gA + r*rnd, As[0] + r*2048 + t*8);
  #pragma unroll
  for (int r=0;r<4;++r)  async16(gB + r*rnd, Bs[0] + r*2048 + t*8);

  int sw8 = (lr&7);
  for (int kt=0; kt<nk; ++kt){
    int cur = kt&1;
    __syncthreads();
    if (kt+1 < nk){
      int ko = (kt+1)<<6;
      #pragma unroll
      for (int r=0;r<MI;++r) async16(gA + r*rnd + ko, As[cur^1] + r*2048 + t*8);
      #pragma unroll
      for (int r=0;r<4;++r)  async16(gB + r*rnd + ko, Bs[cur^1] + r*2048 + t*8);
    }
    const u16* as = As[cur];
    const u16* bs = Bs[cur];
    #pragma unroll
    for (int kk=0;kk<2;++kk){
      int so = (((kk*4+lq)^sw8))<<3;
      short8 a[MI], b[4];
      #pragma unroll
      for (int i=0;i<MI;++i) a[i] = *(const short8*)(as + (wm+i*16+lr)*64 + so);
      #pragma unroll
      for (int j=0;j<4;++j)  b[j] = *(const short8*)(bs + (wn+j*16+lr)*64 + so);
      #pragma unroll
      for (int i=0;i<MI;++i)
        #pragma unroll
        for (int j=0;j<4;++j)
          acc[i][j] = __builtin_amdgcn_mfma_f32_16x16x32_bf16(a[i], b[j], acc[i][j], 0,0,0);
    }
  }

  #pragma unroll
  for (int i=0;i<MI;++i){
    #pragma unroll
    for (int j=0;j<4;++j){
      int col = col0 + wn + j*16 + lr;
      float bv = bias ? bias[col] : 0.0f;
      #pragma unroll
      for (int r=0;r<4;++r){
        int row = row0 + wm + i*16 + lq*4 + r;
        float v = acc[i][j][r] + bv;
        if (do_relu) v = fmaxf(v, 0.0f);
        if (residual) v += b2f(residual[(size_t)row*N + col]);
        if (Cf) Cf[(size_t)row*N + col] = v;
        else    C [(size_t)row*N + col] = f2b(v);
      }
    }
  }
}

// ---------------- causal flash attention v4 ----------------
// Q-tile 64 (4 waves x 16 q rows), s-tile 64 double-buffered, grid 1024.
// S^T via K=32 mfma; P stays IN-LANE (C-layout == K=16 A-layout), PV via
// 16x16x16 mfma on packed bf16 — no P LDS round-trip. Complementary-qt
// slot pairing balances per-CU work. K and V^T staged via global_load_lds.
__global__ __launch_bounds__(256,4) void attn_kernel(const u16* __restrict__ QKV,
    const u16* __restrict__ VT, u16* __restrict__ O)
{
  const int T=2048, LD=3072, E=1024;
  int bid = blockIdx.y * gridDim.x + blockIdx.x;
  int xcd = bid & 7, slot = bid >> 3;
  int idx = slot & 31, grp = slot >> 5;
  int qt = (grp & 1) ? idx : 31 - idx;   // heavy-first, complementary pairing
  int bh = xcd*4 + grp;
  int bb = bh>>4, h = bh&15;
  const u16* base = QKV + (size_t)bb*T*LD;
  const u16* Qp = base + h*64;
  const u16* Kp = base + 1024 + h*64;
  const u16* Vtp = VT + (size_t)bh*64*2048;
  int t = threadIdx.x, l = t&63, w = t>>6;
  int lr = l&15, lq = l>>4;

  __shared__ __align__(16) u16 Ks[2][64*64];   // [s][d], chunk c at slot c^(s&7)
  __shared__ __align__(16) u16 Vs[2][64*64];   // [d][s], chunk c at slot c^(d&7)

  const float QSC = 0.125f*1.44269504f;
  int q0 = qt*64 + w*16;
  short8 aq[2];
  #pragma unroll
  for (int kk=0;kk<2;++kk){
    short8 raw = *(const short8*)(Qp + (size_t)(q0+lr)*LD + kk*32 + lq*8);
    short8 sc;
    #pragma unroll
    for (int j=0;j<8;++j) sc[j] = (short)f2b(b2f((u16)raw[j])*QSC);
    aq[kk]=sc;
  }

  float mrun = -3e38f, lrun = 0.f;
  f32x4 Oacc[4];
  #pragma unroll
  for (int dt=0;dt<4;++dt) Oacc[dt] = f32x4{0.f,0.f,0.f,0.f};

  int kc = (l&7) ^ (l>>3);
  int ra = 8*w + (l>>3);

  // prologue: stage tile 0
  async16(Kp  + (size_t)ra*LD        + kc*8, Ks[0] + t*8);
  async16(Kp  + (size_t)(ra+32)*LD   + kc*8, Ks[0] + 2048 + t*8);
  async16(Vtp + (size_t)ra*2048      + kc*8, Vs[0] + t*8);
  async16(Vtp + (size_t)(ra+32)*2048 + kc*8, Vs[0] + 2048 + t*8);

  for (int it=0; it<=qt; ++it){
    int s0 = it*64, cur = it&1;
    __syncthreads();
    if (it < qt){
      int sn = s0+64;
      u16* kd = Ks[cur^1]; u16* vd = Vs[cur^1];
      async16(Kp  + (size_t)(sn+ra)*LD        + kc*8, kd + t*8);
      async16(Kp  + (size_t)(sn+ra+32)*LD     + kc*8, kd + 2048 + t*8);
      async16(Vtp + (size_t)ra*2048      + sn + kc*8, vd + t*8);
      async16(Vtp + (size_t)(ra+32)*2048 + sn + kc*8, vd + 2048 + t*8);
    }
    const u16* ks = Ks[cur];
    const u16* vs = Vs[cur];

    // S^T[s][q] for this wave's 16 q
    f32x4 S[4];
    #pragma unroll
    for (int st=0; st<4; ++st){
      short8 kf0 = *(const short8*)(ks + (st*16+lr)*64 + ((lq  )^(lr&7))*8);
      short8 kf1 = *(const short8*)(ks + (st*16+lr)*64 + ((4+lq)^(lr&7))*8);
      f32x4 z = f32x4{0.f,0.f,0.f,0.f};
      z = __builtin_amdgcn_mfma_f32_16x16x32_bf16(kf0, aq[0], z, 0,0,0);
      z = __builtin_amdgcn_mfma_f32_16x16x32_bf16(kf1, aq[1], z, 0,0,0);
      S[st] = z;
    }
    if (it == qt){
      int qg = q0 + lr;
      #pragma unroll
      for (int st=0;st<4;++st)
        #pragma unroll
        for (int r=0;r<4;++r){
          int sg = s0 + st*16 + lq*4 + r;
          if (sg > qg) S[st][r] = -3e38f;
        }
    }
    // online softmax (q = lr; s-reduction in-lane + 2 shuffles)
    float m = S[0][0];
    #pragma unroll
    for (int st=0;st<4;++st)
      #pragma unroll
      for (int r=0;r<4;++r) m = fmaxf(m, S[st][r]);
    m = fmaxf(m, __shfl_xor(m,16));
    m = fmaxf(m, __shfl_xor(m,32));
    float mnew = fmaxf(mrun, m);
    float alpha = EXP2F(mrun - mnew);
    mrun = mnew;
    float ssum = 0.f;
    #pragma unroll
    for (int st=0;st<4;++st)
      #pragma unroll
      for (int r=0;r<4;++r){ float p = EXP2F(S[st][r]-mnew); S[st][r]=p; ssum+=p; }
    ssum += __shfl_xor(ssum,16);
    ssum += __shfl_xor(ssum,32);
    lrun = lrun*alpha + ssum;
    // P: in-lane pack to K=16 A-fragments
    short4_t pk[4];
    #pragma unroll
    for (int st=0;st<4;++st) pk[st] = pack4(S[st]);
    // rescale O (O rows: q = lq*4+r)
    float af[4];
    #pragma unroll
    for (int r=0;r<4;++r) af[r] = __shfl(alpha, lq*4+r);
    #pragma unroll
    for (int dt=0;dt<4;++dt)
      #pragma unroll
      for (int r=0;r<4;++r) Oacc[dt][r] *= af[r];
    // PV: 16 x mfma_16x16x16
    #pragma unroll
    for (int st=0;st<4;++st){
      #pragma unroll
      for (int dt=0;dt<4;++dt){
        short4_t vf = *(const short4_t*)(vs + (dt*16+lr)*64 + ((2*st+(lq>>1))^(lr&7))*8 + (lq&1)*4);
        Oacc[dt] = MFMA16(pk[st], vf, Oacc[dt]);
      }
    }
  }
  float linv[4];
  #pragma unroll
  for (int r=0;r<4;++r) linv[r] = 1.0f/__shfl(lrun, lq*4+r);
  #pragma unroll
  for (int dt=0;dt<4;++dt)
    #pragma unroll
    for (int r=0;r<4;++r){
      int qg = q0 + lq*4 + r;
      O[(size_t)(bb*T+qg)*E + h*64 + dt*16 + lr] = f2b(Oacc[dt][r]*linv[r]);
    }
}

// ---------------- host ----------------
extern "C" void kernel_launch(void* const* d_in, const int* in_sizes, int n_in,
                              void* d_out, int out_size, void* d_ws, size_t ws_size,
                              hipStream_t stream)
{
  (void)in_sizes; (void)n_in; (void)out_size; (void)ws_size;
  const float* x     = (const float*)d_in[0];
  const float* wq    = (const float*)d_in[1];
  const float* wk    = (const float*)d_in[2];
  const float* wv    = (const float*)d_in[3];
  const float* wproj = (const float*)d_in[4];
  const float* bproj = (const float*)d_in[5];
  const float* g1    = (const float*)d_in[6];
  const float* be1   = (const float*)d_in[7];
  const float* g2    = (const float*)d_in[8];
  const float* be2   = (const float*)d_in[9];
  const float* w1    = (const float*)d_in[10];
  const float* b1    = (const float*)d_in[11];
  const float* w2    = (const float*)d_in[12];
  const float* b2    = (const float*)d_in[13];
  float* out = (float*)d_out;

  char* ws = (char*)d_ws;
  size_t off = 0;
  auto alloc = [&](size_t bytes)->void*{ void* p = ws + off; off += (bytes + 255) & ~(size_t)255; return p; };
  u16* hnorm  = (u16*)alloc((size_t)4096*1024*2);
  u16* qkv    = (u16*)alloc((size_t)4096*3072*2);
  u16* VT     = (u16*)alloc((size_t)32*64*2048*2);
  u16* attnO  = (u16*)alloc((size_t)4096*1024*2);
  u16* x2     = (u16*)alloc((size_t)4096*1024*2);
  u16* h2     = (u16*)alloc((size_t)4096*1024*2);
  u16* ffn1   = (u16*)alloc((size_t)4096*4096*2);
  u16* wqkvT  = (u16*)alloc((size_t)3072*1024*2);
  u16* wprojT = (u16*)alloc((size_t)1024*1024*2);
  u16* w1T    = (u16*)alloc((size_t)4096*1024*2);
  u16* w2T    = (u16*)alloc((size_t)1024*4096*2);

  qkv_repack  <<<dim3(16,48),256,0,stream>>>(wq,wk,wv,wqkvT);
  transpose_bt<<<dim3(16,16),256,0,stream>>>(wproj, wprojT, 1024, 1024);
  transpose_bt<<<dim3(64,16),256,0,stream>>>(w1,    w1T,    4096, 1024);
  transpose_bt<<<dim3(16,64),256,0,stream>>>(w2,    w2T,    1024, 4096);

  ln_kernel<1><<<4096,256,0,stream>>>(x, g1, be1, hnorm);
  gemm_bt<4><<<dim3(24,32),256,0,stream>>>(hnorm, wqkvT, qkv, nullptr, 4096,3072,1024, nullptr, nullptr, 0, 8);
  vtrans<<<dim3(32,32),256,0,stream>>>(qkv, VT);
  attn_kernel<<<dim3(32,32),256,0,stream>>>(qkv, VT, attnO);
  gemm_bt<2><<<dim3(8,64),256,0,stream>>>(attnO, wprojT, x2, nullptr, 4096,1024,1024, bproj, hnorm, 0, 2);
  ln_kernel<0><<<4096,256,0,stream>>>(x2, g2, be2, h2);
  gemm_bt<4><<<dim3(32,32),256,0,stream>>>(h2, w1T, ffn1, nullptr, 4096,4096,1024, b1, nullptr, 1, 8);
  gemm_bt<2><<<dim3(8,64),256,0,stream>>>(ffn1, w2T, nullptr, out, 4096,1024,4096, b2, h2, 0, 2);
}